// Round 1
// baseline (3498.761 us; speedup 1.0000x reference)
//
#include <hip/hip_runtime.h>
#include <hip/hip_bf16.h>
#include <math.h>

typedef unsigned short ushort8 __attribute__((ext_vector_type(8)));

constexpr int NE = 768;      // N_EMBD
constexpr int NH = 12;       // heads
constexpr int HD = 64;       // head dim
constexpr int Bc = 4;
constexpr int Tc = 1024;
constexpr int BT = Bc * Tc;  // 4096 rows

// ---------------- LayerNorm: f32 in -> bf16 out ----------------
__global__ __launch_bounds__(256) void ln_kernel(const float* __restrict__ x,
                                                 const float* __restrict__ w,
                                                 const float* __restrict__ b,
                                                 __hip_bfloat16* __restrict__ out) {
    int row = blockIdx.x;
    const float* xr = x + (size_t)row * NE;
    int t = threadIdx.x;
    float v0 = xr[t], v1 = xr[t + 256], v2 = xr[t + 512];
    __shared__ float red[256], red2[256];
    red[t] = v0 + v1 + v2;
    red2[t] = v0 * v0 + v1 * v1 + v2 * v2;
    __syncthreads();
    for (int o = 128; o > 0; o >>= 1) {
        if (t < o) { red[t] += red[t + o]; red2[t] += red2[t + o]; }
        __syncthreads();
    }
    float mean = red[0] * (1.0f / NE);
    float var = red2[0] * (1.0f / NE) - mean * mean;
    float rs = rsqrtf(var + 1e-5f);
    __hip_bfloat16* orow = out + (size_t)row * NE;
    orow[t]       = __float2bfloat16((v0 - mean) * rs * w[t]       + b[t]);
    orow[t + 256] = __float2bfloat16((v1 - mean) * rs * w[t + 256] + b[t + 256]);
    orow[t + 512] = __float2bfloat16((v2 - mean) * rs * w[t + 512] + b[t + 512]);
}

// ---------------- GEMM: C = A(bf16, MxK) @ W(f32, KxN) + bias ----------------
// OUT_MODE: 0 = f32 to Cf, 1 = bf16 to Cb, 2 = qkv scatter to Qo/Ko/Vo [b,h,t,d]
// ACT: 0 none, 1 exact gelu.  RES: add residual (f32, MxN), may alias Cf.
template <int OUT_MODE, int ACT, bool RES>
__global__ __launch_bounds__(256) void gemm_kernel(
    const __hip_bfloat16* __restrict__ A, const float* __restrict__ W,
    const float* __restrict__ bias, const float* residual, float* Cf,
    __hip_bfloat16* __restrict__ Cb,
    __hip_bfloat16* __restrict__ Qo, __hip_bfloat16* __restrict__ Ko,
    __hip_bfloat16* __restrict__ Vo,
    int M, int N, int K) {
    constexpr int BM = 128, BN = 128, BK = 16;
    __shared__ float As[BM][BK + 1];
    __shared__ __align__(16) float Ws[BK][132];
    int tid = threadIdx.x;
    int n0 = blockIdx.x * BN, m0 = blockIdx.y * BM;
    int tx = tid & 15, ty = tid >> 4;
    float acc[8][8] = {};
    for (int k0 = 0; k0 < K; k0 += BK) {
#pragma unroll
        for (int it = 0; it < 8; ++it) {
            int i = tid + it * 256;
            int r = i >> 4, c = i & 15;
            As[r][c] = __bfloat162float(A[(size_t)(m0 + r) * K + k0 + c]);
        }
#pragma unroll
        for (int it = 0; it < 8; ++it) {
            int i = tid + it * 256;
            int r = i >> 7, c = i & 127;
            Ws[r][c] = W[(size_t)(k0 + r) * N + n0 + c];
        }
        __syncthreads();
#pragma unroll
        for (int kk = 0; kk < BK; ++kk) {
            float a[8], bb[8];
#pragma unroll
            for (int i = 0; i < 8; ++i) a[i] = As[ty * 8 + i][kk];
            float4 b0 = *reinterpret_cast<const float4*>(&Ws[kk][tx * 8]);
            float4 b1 = *reinterpret_cast<const float4*>(&Ws[kk][tx * 8 + 4]);
            bb[0] = b0.x; bb[1] = b0.y; bb[2] = b0.z; bb[3] = b0.w;
            bb[4] = b1.x; bb[5] = b1.y; bb[6] = b1.z; bb[7] = b1.w;
#pragma unroll
            for (int i = 0; i < 8; ++i)
#pragma unroll
                for (int j = 0; j < 8; ++j) acc[i][j] += a[i] * bb[j];
        }
        __syncthreads();
    }
#pragma unroll
    for (int i = 0; i < 8; ++i) {
        int m = m0 + ty * 8 + i;
#pragma unroll
        for (int j = 0; j < 8; ++j) {
            int n = n0 + tx * 8 + j;
            float v = acc[i][j] + bias[n];
            if (ACT == 1) v = 0.5f * v * (1.0f + erff(v * 0.70710678118654752f));
            if (RES) v += residual[(size_t)m * N + n];
            if (OUT_MODE == 0) {
                Cf[(size_t)m * N + n] = v;
            } else if (OUT_MODE == 1) {
                Cb[(size_t)m * N + n] = __float2bfloat16(v);
            } else {
                int which = n / NE;
                int rem = n - which * NE;
                int h = rem >> 6, d = rem & 63;
                int bb_ = m >> 10, t_ = m & 1023;
                __hip_bfloat16* dst = which == 0 ? Qo : (which == 1 ? Ko : Vo);
                dst[((size_t)(bb_ * NH + h) * Tc + t_) * HD + d] = __float2bfloat16(v);
            }
        }
    }
}

// ---------------- attention helpers ----------------
__device__ __forceinline__ void load_row64(const __hip_bfloat16* p, float* dst) {
    const ushort8* r = reinterpret_cast<const ushort8*>(p);
#pragma unroll
    for (int c = 0; c < 8; ++c) {
        ushort8 u = r[c];
#pragma unroll
        for (int e = 0; e < 8; ++e)
            dst[c * 8 + e] = __uint_as_float(((unsigned)u[e]) << 16);
    }
}

__device__ __forceinline__ float dot_qk(const float* qreg, const __hip_bfloat16* krow) {
    const ushort8* kr = reinterpret_cast<const ushort8*>(krow);
    float s = 0.f;
#pragma unroll
    for (int c = 0; c < 8; ++c) {
        ushort8 u = kr[c];
#pragma unroll
        for (int e = 0; e < 8; ++e)
            s += qreg[c * 8 + e] * __uint_as_float(((unsigned)u[e]) << 16);
    }
    return s * 0.125f;  // 1/sqrt(64)
}

// pass 1+2: per-row softmax stats (max, denom) + column sums of probs
__global__ __launch_bounds__(256) void attn_pass12(
    const __hip_bfloat16* __restrict__ Qp, const __hip_bfloat16* __restrict__ Kp,
    float2* __restrict__ rowstats, float* __restrict__ colsum) {
    int blk = blockIdx.x;
    int bh = blk >> 4, qc = blk & 15;
    int wave = threadIdx.x >> 6, lane = threadIdx.x & 63;
    __shared__ float cs[4][1024];
    for (int i = threadIdx.x; i < 4 * 1024; i += 256) ((float*)cs)[i] = 0.f;
    __syncthreads();
    const __hip_bfloat16* Qb = Qp + (size_t)bh * Tc * HD;
    const __hip_bfloat16* Kb = Kp + (size_t)bh * Tc * HD;
    for (int r = 0; r < 16; ++r) {
        int q = qc * 64 + r * 4 + wave;
        float qreg[64];
        load_row64(Qb + (size_t)q * HD, qreg);
        float sc[16];
        float mloc = -1e30f;
#pragma unroll
        for (int i = 0; i < 16; ++i) {
            int k = lane + (i << 6);
            float s = 0.f;
            if (k <= q) {
                s = dot_qk(qreg, Kb + (size_t)k * HD);
                mloc = fmaxf(mloc, s);
            }
            sc[i] = s;
        }
#pragma unroll
        for (int o = 32; o > 0; o >>= 1) mloc = fmaxf(mloc, __shfl_xor(mloc, o));
        float ssum = 0.f;
#pragma unroll
        for (int i = 0; i < 16; ++i) {
            int k = lane + (i << 6);
            if (k <= q) { sc[i] = expf(sc[i] - mloc); ssum += sc[i]; }
            else sc[i] = 0.f;
        }
        float tot = ssum;
#pragma unroll
        for (int o = 32; o > 0; o >>= 1) tot += __shfl_xor(tot, o);
        if (lane == 0) rowstats[(size_t)bh * Tc + q] = make_float2(mloc, tot);
        float inv = 1.f / tot;
#pragma unroll
        for (int i = 0; i < 16; ++i) cs[wave][lane + (i << 6)] += sc[i] * inv;
    }
    __syncthreads();
    for (int k = threadIdx.x; k < 1024; k += 256) {
        float tot = cs[0][k] + cs[1][k] + cs[2][k] + cs[3][k];
        atomicAdd(&colsum[(size_t)bh * Tc + k], tot);
    }
}

// pass 3: recompute probs, LIF-modulate, renormalize, PV, new_refractory
__global__ __launch_bounds__(256) void attn_pass3(
    const __hip_bfloat16* __restrict__ Qp, const __hip_bfloat16* __restrict__ Kp,
    const __hip_bfloat16* __restrict__ Vp,
    const float2* __restrict__ rowstats, const float* __restrict__ colsum,
    const float* __restrict__ refr_in,
    const float* __restrict__ threshold, const float* __restrict__ leak,
    const float* __restrict__ steepness, const float* __restrict__ refractory_strength,
    const float* __restrict__ cross_layer_weight,
    __hip_bfloat16* __restrict__ Yout, float* __restrict__ refr_out) {
    int blk = blockIdx.x;
    int bh = blk >> 4, qc = blk & 15;
    int b = bh / NH, h = bh % NH;
    int wave = threadIdx.x >> 6, lane = threadIdx.x & 63;
    __shared__ float rf[4][1024];
    __shared__ float eff[1024];
    float thr = fabsf(threshold[h]) * 0.1f;
    float lk = 1.f / (1.f + expf(-leak[h]));
    float sx = steepness[h];
    float stp = (sx > 20.f) ? sx : log1pf(expf(sx));
    float rx = refractory_strength[h];
    float refs = (rx > 20.f) ? rx : log1pf(expf(rx));
    float crw = 1.f / (1.f + expf(-cross_layer_weight[h]));
    for (int i = threadIdx.x; i < 4 * 1024; i += 256) ((float*)rf)[i] = 0.f;
    for (int k = threadIdx.x; k < 1024; k += 256)
        eff[k] = thr + refs * (colsum[(size_t)bh * Tc + k] * (1.f / Tc))
                     + crw * refr_in[(size_t)b * Tc + k];
    __syncthreads();
    const __hip_bfloat16* Qb = Qp + (size_t)bh * Tc * HD;
    const __hip_bfloat16* Kb = Kp + (size_t)bh * Tc * HD;
    const __hip_bfloat16* Vb = Vp + (size_t)bh * Tc * HD;
    for (int r = 0; r < 16; ++r) {
        int q = qc * 64 + r * 4 + wave;
        float qreg[64];
        load_row64(Qb + (size_t)q * HD, qreg);
        float2 st = rowstats[(size_t)bh * Tc + q];
        float inv = 1.f / st.y;
        float sc[16];
#pragma unroll
        for (int i = 0; i < 16; ++i) {
            int k = lane + (i << 6);
            float p = 0.f;
            if (k <= q) {
                float s = dot_qk(qreg, Kb + (size_t)k * HD);
                p = expf(s - st.x) * inv;
                float fire = 1.f / (1.f + expf(-stp * (p - eff[k])));
                float w = fire + lk * (1.f - fire);
                p = p * w;
            }
            sc[i] = p;
        }
        float ms = 0.f;
#pragma unroll
        for (int i = 0; i < 16; ++i) ms += sc[i];
#pragma unroll
        for (int o = 32; o > 0; o >>= 1) ms += __shfl_xor(ms, o);
        float scale = 1.f / (ms + 1e-8f);
        float y = 0.f;
#pragma unroll
        for (int i = 0; i < 16; ++i) {
            sc[i] *= scale;
            rf[wave][lane + (i << 6)] += sc[i];
        }
#pragma unroll
        for (int i = 0; i < 16; ++i) {
            if ((i << 6) > q) break;  // wave-uniform
            float mv = sc[i];
            const __hip_bfloat16* vb = Vb + ((size_t)(i << 6)) * HD + lane;
            for (int j = 0; j < 64; ++j) {
                float m_ = __shfl(mv, j);
                y += m_ * __bfloat162float(vb[(size_t)j * HD]);
            }
        }
        Yout[((size_t)(b * Tc + q)) * NE + h * HD + lane] = __float2bfloat16(y);
    }
    __syncthreads();
    for (int k = threadIdx.x; k < 1024; k += 256) {
        float tot = (rf[0][k] + rf[1][k] + rf[2][k] + rf[3][k]) * (1.f / (NH * Tc));
        atomicAdd(&refr_out[(size_t)b * Tc + k], tot);
    }
}

// ---------------- launcher ----------------
extern "C" void kernel_launch(void* const* d_in, const int* in_sizes, int n_in,
                              void* d_out, int out_size, void* d_ws, size_t ws_size,
                              hipStream_t stream) {
    const float* x        = (const float*)d_in[0];
    const float* refr     = (const float*)d_in[1];
    const float* ln1_w    = (const float*)d_in[2];
    const float* ln1_b    = (const float*)d_in[3];
    const float* c_attn_w = (const float*)d_in[4];
    const float* c_attn_b = (const float*)d_in[5];
    const float* c_proj_w = (const float*)d_in[6];
    const float* c_proj_b = (const float*)d_in[7];
    const float* threshold = (const float*)d_in[8];
    const float* leak      = (const float*)d_in[9];
    const float* steepness = (const float*)d_in[10];
    const float* refractory_strength = (const float*)d_in[11];
    const float* cross_layer_weight  = (const float*)d_in[12];
    const float* ln2_w    = (const float*)d_in[13];
    const float* ln2_b    = (const float*)d_in[14];
    const float* fc_w     = (const float*)d_in[15];
    const float* fc_b     = (const float*)d_in[16];
    const float* proj_w   = (const float*)d_in[17];
    const float* proj_b   = (const float*)d_in[18];

    // workspace layout (bytes):
    //   h       [0,        6291456)  bf16 BT*NE   (LN1 out, reused for LN2 out)
    //   q       [6291456, 12582912)  bf16 [b,h,t,d]
    //   k       [12582912,18874368)
    //   v       [18874368,25165824)
    //   fc_act  [6291456, 31457280)  bf16 BT*4NE  (overlaps qkv; used after attn)
    //   y       [31457280,37748736)  bf16 BT*NE
    //   rowstats[37748736,38141952)  float2 B*H*T
    //   colsum  [38141952,38338560)  f32 B*H*T
    char* ws = (char*)d_ws;
    __hip_bfloat16* hbuf   = (__hip_bfloat16*)(ws + 0);
    __hip_bfloat16* qb     = (__hip_bfloat16*)(ws + 6291456);
    __hip_bfloat16* kb     = (__hip_bfloat16*)(ws + 12582912);
    __hip_bfloat16* vb     = (__hip_bfloat16*)(ws + 18874368);
    __hip_bfloat16* fc_act = (__hip_bfloat16*)(ws + 6291456);
    __hip_bfloat16* ybuf   = (__hip_bfloat16*)(ws + 31457280);
    float2* rowstats       = (float2*)(ws + 37748736);
    float* colsum          = (float*)(ws + 38141952);

    float* xout = (float*)d_out;
    float* refr_out = xout + (size_t)BT * NE;

    hipMemsetAsync(colsum, 0, (size_t)Bc * NH * Tc * sizeof(float), stream);
    hipMemsetAsync(refr_out, 0, (size_t)Bc * Tc * sizeof(float), stream);

    ln_kernel<<<BT, 256, 0, stream>>>(x, ln1_w, ln1_b, hbuf);

    gemm_kernel<2, 0, false><<<dim3(18, 32), 256, 0, stream>>>(
        hbuf, c_attn_w, c_attn_b, nullptr, nullptr, nullptr, qb, kb, vb,
        BT, 3 * NE, NE);

    attn_pass12<<<Bc * NH * 16, 256, 0, stream>>>(qb, kb, rowstats, colsum);

    attn_pass3<<<Bc * NH * 16, 256, 0, stream>>>(
        qb, kb, vb, rowstats, colsum, refr, threshold, leak, steepness,
        refractory_strength, cross_layer_weight, ybuf, refr_out);

    gemm_kernel<0, 0, true><<<dim3(6, 32), 256, 0, stream>>>(
        ybuf, c_proj_w, c_proj_b, x, xout, nullptr, nullptr, nullptr, nullptr,
        BT, NE, NE);

    ln_kernel<<<BT, 256, 0, stream>>>(xout, ln2_w, ln2_b, hbuf);

    gemm_kernel<1, 1, false><<<dim3(24, 32), 256, 0, stream>>>(
        hbuf, fc_w, fc_b, nullptr, nullptr, fc_act, nullptr, nullptr, nullptr,
        BT, 4 * NE, NE);

    gemm_kernel<0, 0, true><<<dim3(6, 32), 256, 0, stream>>>(
        fc_act, proj_w, proj_b, xout, xout, nullptr, nullptr, nullptr, nullptr,
        BT, NE, 4 * NE);
}

// Round 2
// 455.705 us; speedup vs baseline: 7.6777x; 7.6777x over previous
//
#include <hip/hip_runtime.h>
#include <hip/hip_bf16.h>
#include <math.h>

typedef unsigned short ushort;
typedef __attribute__((ext_vector_type(8))) unsigned short ushort8;
typedef __attribute__((ext_vector_type(8))) short s16x8;
typedef __attribute__((ext_vector_type(4))) float f32x4;

constexpr int NE = 768;      // N_EMBD
constexpr int NH = 12;       // heads
constexpr int HD = 64;       // head dim
constexpr int Bc = 4;
constexpr int Tc = 1024;
constexpr int BT = Bc * Tc;  // 4096 rows

__device__ __forceinline__ ushort f2bf(float f) {
    __hip_bfloat16 h = __float2bfloat16(f);
    return *reinterpret_cast<ushort*>(&h);
}
__device__ __forceinline__ float softplus_f(float x) {
    return (x > 20.f) ? x : log1pf(__expf(x));
}
__device__ __forceinline__ void gload16(const void* g, void* l) {
    __builtin_amdgcn_global_load_lds((const __attribute__((address_space(1))) void*)g,
                                     (__attribute__((address_space(3))) void*)l, 16, 0, 0);
}

// ---------------- LayerNorm: f32 in -> bf16 out ----------------
__global__ __launch_bounds__(256) void ln_kernel(const float* __restrict__ x,
                                                 const float* __restrict__ w,
                                                 const float* __restrict__ b,
                                                 ushort* __restrict__ out) {
    int row = blockIdx.x;
    const float* xr = x + (size_t)row * NE;
    int t = threadIdx.x;
    float v0 = xr[t], v1 = xr[t + 256], v2 = xr[t + 512];
    __shared__ float red[256], red2[256];
    red[t] = v0 + v1 + v2;
    red2[t] = v0 * v0 + v1 * v1 + v2 * v2;
    __syncthreads();
    for (int o = 128; o > 0; o >>= 1) {
        if (t < o) { red[t] += red[t + o]; red2[t] += red2[t + o]; }
        __syncthreads();
    }
    float mean = red[0] * (1.0f / NE);
    float var = red2[0] * (1.0f / NE) - mean * mean;
    float rs = rsqrtf(var + 1e-5f);
    ushort* orow = out + (size_t)row * NE;
    orow[t]       = f2bf((v0 - mean) * rs * w[t]       + b[t]);
    orow[t + 256] = f2bf((v1 - mean) * rs * w[t + 256] + b[t + 256]);
    orow[t + 512] = f2bf((v2 - mean) * rs * w[t + 512] + b[t + 512]);
}

// ---------------- weight convert: W f32 [K][N] -> Wt bf16 [N][K] ----------------
__global__ __launch_bounds__(256) void wconvert(const float* __restrict__ W,
                                                ushort* __restrict__ Wt, int K, int N) {
    __shared__ float t[32][33];
    int n0 = blockIdx.x * 32, k0 = blockIdx.y * 32;
    int c = threadIdx.x & 31, r4 = threadIdx.x >> 5;
#pragma unroll
    for (int i = 0; i < 4; ++i) {
        int r = r4 + i * 8;
        t[r][c] = W[(size_t)(k0 + r) * N + n0 + c];
    }
    __syncthreads();
#pragma unroll
    for (int i = 0; i < 4; ++i) {
        int r = r4 + i * 8;
        Wt[(size_t)(n0 + r) * K + k0 + c] = f2bf(t[c][r]);
    }
}

// ---------------- MFMA GEMM: C[M][N] = A(bf16 [M][K]) @ Bt(bf16 [N][K])^T + bias ----------------
// OUT_MODE: 0 = f32 to Cf, 1 = bf16 to Cb, 2 = qkv scatter. ACT: 1 = exact gelu. RES: +residual f32.
template <int OUT_MODE, int ACT, bool RES>
__global__ __launch_bounds__(256) void mfma_gemm(
    const ushort* __restrict__ A, const ushort* __restrict__ Bt,
    const float* __restrict__ bias, const float* __restrict__ residual,
    float* __restrict__ Cf, ushort* __restrict__ Cb,
    ushort* __restrict__ Qo, ushort* __restrict__ Ko, ushort* __restrict__ Vo,
    int M, int N, int K) {
    __shared__ __align__(16) ushort As[128 * 32];
    __shared__ __align__(16) ushort Bs[128 * 32];
    int tid = threadIdx.x;
    int lane = tid & 63;
    int m0 = blockIdx.y * 128, n0 = blockIdx.x * 128;
    int wave = tid >> 6;
    int wr = wave >> 1, wc = wave & 1;
    f32x4 acc[4][4] = {};
    const int sr = tid >> 2, sc8 = tid & 3;
    const ushort* ga = A + (size_t)(m0 + sr) * K + sc8 * 8;
    const ushort* gb = Bt + (size_t)(n0 + sr) * K + sc8 * 8;
    char* lA = (char*)As + (tid & 192) * 16;
    char* lB = (char*)Bs + (tid & 192) * 16;
    const char* ab = (const char*)As + ((wr << 6) + (lane & 15)) * 64 + ((lane >> 4) << 4);
    const char* bb = (const char*)Bs + ((wc << 6) + (lane & 15)) * 64 + ((lane >> 4) << 4);
    for (int k0 = 0; k0 < K; k0 += 32) {
        gload16(ga + k0, lA);
        gload16(ga + (size_t)64 * K + k0, lA + 4096);
        gload16(gb + k0, lB);
        gload16(gb + (size_t)64 * K + k0, lB + 4096);
        __syncthreads();
        s16x8 af[4], bf[4];
#pragma unroll
        for (int i = 0; i < 4; ++i) {
            af[i] = *(const s16x8*)(ab + i * 1024);
            bf[i] = *(const s16x8*)(bb + i * 1024);
        }
#pragma unroll
        for (int mi = 0; mi < 4; ++mi)
#pragma unroll
            for (int ni = 0; ni < 4; ++ni)
                acc[mi][ni] = __builtin_amdgcn_mfma_f32_16x16x32_bf16(af[mi], bf[ni], acc[mi][ni], 0, 0, 0);
        __syncthreads();
    }
#pragma unroll
    for (int mi = 0; mi < 4; ++mi) {
#pragma unroll
        for (int ni = 0; ni < 4; ++ni) {
#pragma unroll
            for (int j = 0; j < 4; ++j) {
                int row = m0 + wr * 64 + mi * 16 + (lane >> 4) * 4 + j;
                int col = n0 + wc * 64 + ni * 16 + (lane & 15);
                float v = acc[mi][ni][j] + bias[col];
                if (ACT == 1) v = 0.5f * v * (1.0f + erff(v * 0.70710678118654752f));
                if (RES) v += residual[(size_t)row * N + col];
                if (OUT_MODE == 0) {
                    Cf[(size_t)row * N + col] = v;
                } else if (OUT_MODE == 1) {
                    Cb[(size_t)row * N + col] = f2bf(v);
                } else {
                    int which = col >= 1536 ? 2 : (col >= 768 ? 1 : 0);
                    int rem = col - which * 768;
                    int h = rem >> 6, d = rem & 63;
                    int b_ = row >> 10, t_ = row & 1023;
                    ushort* dst = which == 0 ? Qo : (which == 1 ? Ko : Vo);
                    dst[((size_t)(b_ * NH + h) * Tc + t_) * HD + d] = f2bf(v);
                }
            }
        }
    }
}

// ---------------- attention: S tile via MFMA ----------------
__device__ __forceinline__ f32x4 qk_tile(const ushort* Kb, int kt, int lane,
                                         s16x8 qf0, s16x8 qf1) {
    const ushort* kr = Kb + (size_t)(kt * 16 + (lane & 15)) * HD + ((lane >> 4) << 3);
    s16x8 k0 = *(const s16x8*)kr;
    s16x8 k1 = *(const s16x8*)(kr + 32);
    f32x4 z = {0.f, 0.f, 0.f, 0.f};
    z = __builtin_amdgcn_mfma_f32_16x16x32_bf16(qf0, k0, z, 0, 0, 0);
    z = __builtin_amdgcn_mfma_f32_16x16x32_bf16(qf1, k1, z, 0, 0, 0);
    return z;
}

// A1: per-row softmax stats (max, denom), online over key tiles.
__global__ __launch_bounds__(256) void attn_rowstats(
    const ushort* __restrict__ Qp, const ushort* __restrict__ Kp,
    float2* __restrict__ rowstats) {
    int bh = blockIdx.x >> 4, qc = blockIdx.x & 15;
    int wave = threadIdx.x >> 6, lane = threadIdx.x & 63;
    int q0 = qc * 64 + wave * 16;
    int qbase = q0 + ((lane >> 4) << 2);
    const ushort* Qb = Qp + (size_t)bh * Tc * HD;
    const ushort* Kb = Kp + (size_t)bh * Tc * HD;
    const ushort* qr = Qb + (size_t)(q0 + (lane & 15)) * HD + ((lane >> 4) << 3);
    s16x8 qf0 = *(const s16x8*)qr;
    s16x8 qf1 = *(const s16x8*)(qr + 32);
    float m4[4] = {-1e30f, -1e30f, -1e30f, -1e30f};
    float d4[4] = {0.f, 0.f, 0.f, 0.f};
    int ktmax = qc * 4 + wave;
    for (int kt = 0; kt <= ktmax; ++kt) {
        f32x4 s = qk_tile(Kb, kt, lane, qf0, qf1);
        int key = kt * 16 + (lane & 15);
#pragma unroll
        for (int j = 0; j < 4; ++j) {
            float sv = (key <= qbase + j) ? s[j] * 0.125f : -3e38f;
            float tm = sv;
            tm = fmaxf(tm, __shfl_xor(tm, 1));
            tm = fmaxf(tm, __shfl_xor(tm, 2));
            tm = fmaxf(tm, __shfl_xor(tm, 4));
            tm = fmaxf(tm, __shfl_xor(tm, 8));
            float mn = fmaxf(m4[j], tm);
            float e = __expf(sv - mn);
            float ts = e;
            ts += __shfl_xor(ts, 1);
            ts += __shfl_xor(ts, 2);
            ts += __shfl_xor(ts, 4);
            ts += __shfl_xor(ts, 8);
            d4[j] = d4[j] * __expf(m4[j] - mn) + ts;
            m4[j] = mn;
        }
    }
    if ((lane & 15) == 0) {
#pragma unroll
        for (int j = 0; j < 4; ++j)
            rowstats[(size_t)bh * Tc + qbase + j] = make_float2(m4[j], d4[j]);
    }
}

// A2: column sums of normalized probs (atomics into colsum).
__global__ __launch_bounds__(256) void attn_colsum(
    const ushort* __restrict__ Qp, const ushort* __restrict__ Kp,
    const float2* __restrict__ rowstats, float* __restrict__ colsum) {
    int bh = blockIdx.x >> 4, qc = blockIdx.x & 15;
    int wave = threadIdx.x >> 6, lane = threadIdx.x & 63;
    int q0 = qc * 64 + wave * 16;
    int qbase = q0 + ((lane >> 4) << 2);
    const ushort* Qb = Qp + (size_t)bh * Tc * HD;
    const ushort* Kb = Kp + (size_t)bh * Tc * HD;
    const ushort* qr = Qb + (size_t)(q0 + (lane & 15)) * HD + ((lane >> 4) << 3);
    s16x8 qf0 = *(const s16x8*)qr;
    s16x8 qf1 = *(const s16x8*)(qr + 32);
    float m4[4], invd[4];
#pragma unroll
    for (int j = 0; j < 4; ++j) {
        float2 st = rowstats[(size_t)bh * Tc + qbase + j];
        m4[j] = st.x;
        invd[j] = 1.f / st.y;
    }
    int ktmax = qc * 4 + wave;
    for (int kt = 0; kt <= ktmax; ++kt) {
        f32x4 s = qk_tile(Kb, kt, lane, qf0, qf1);
        int key = kt * 16 + (lane & 15);
        float cs = 0.f;
#pragma unroll
        for (int j = 0; j < 4; ++j) {
            float p = (key <= qbase + j) ? __expf(s[j] * 0.125f - m4[j]) * invd[j] : 0.f;
            cs += p;
        }
        cs += __shfl_xor(cs, 16);
        cs += __shfl_xor(cs, 32);
        if (lane < 16) atomicAdd(&colsum[(size_t)bh * Tc + kt * 16 + lane], cs);
    }
}

// B: modsum sweep + modulated/normalized PV sweep + refractory atomics + Y.
__global__ __launch_bounds__(256) void attn_pv(
    const ushort* __restrict__ Qp, const ushort* __restrict__ Kp,
    const ushort* __restrict__ Vp,
    const float2* __restrict__ rowstats, const float* __restrict__ colsum,
    const float* __restrict__ refr_in,
    const float* __restrict__ threshold, const float* __restrict__ leak,
    const float* __restrict__ steepness, const float* __restrict__ refr_strength,
    const float* __restrict__ cross_w,
    ushort* __restrict__ ybuf, float* __restrict__ refr_out) {
    int bh = blockIdx.x >> 4, qc = blockIdx.x & 15;
    int b = bh / NH, h = bh - b * NH;
    int tid = threadIdx.x, wave = tid >> 6, lane = tid & 63;
    __shared__ float eff[1024];
    __shared__ __align__(16) ushort vt[64][72];
    __shared__ __align__(16) ushort plds[4][16][40];
    float thr = fabsf(threshold[h]) * 0.1f;
    float lk = 1.f / (1.f + __expf(-leak[h]));
    float stp = softplus_f(steepness[h]);
    float rfs = softplus_f(refr_strength[h]);
    float crw = 1.f / (1.f + __expf(-cross_w[h]));
    int kblk = (qc + 1) * 64;
    for (int k = tid; k < kblk; k += 256)
        eff[k] = thr + rfs * (colsum[(size_t)bh * Tc + k] * (1.f / Tc))
                     + crw * refr_in[(size_t)b * Tc + k];
    __syncthreads();
    int q0 = qc * 64 + wave * 16;
    int qbase = q0 + ((lane >> 4) << 2);
    const ushort* Qb = Qp + (size_t)bh * Tc * HD;
    const ushort* Kb = Kp + (size_t)bh * Tc * HD;
    const ushort* Vb = Vp + (size_t)bh * Tc * HD;
    const ushort* qr = Qb + (size_t)(q0 + (lane & 15)) * HD + ((lane >> 4) << 3);
    s16x8 qf0 = *(const s16x8*)qr;
    s16x8 qf1 = *(const s16x8*)(qr + 32);
    float m4[4], invd[4];
#pragma unroll
    for (int j = 0; j < 4; ++j) {
        float2 st = rowstats[(size_t)bh * Tc + qbase + j];
        m4[j] = st.x;
        invd[j] = 1.f / st.y;
    }
    int ktmax = qc * 4 + wave;
    // sweep 1: modulated row sums
    float ms[4] = {0.f, 0.f, 0.f, 0.f};
    for (int kt = 0; kt <= ktmax; ++kt) {
        f32x4 s = qk_tile(Kb, kt, lane, qf0, qf1);
        int key = kt * 16 + (lane & 15);
        float ef = eff[key];
#pragma unroll
        for (int j = 0; j < 4; ++j) {
            float p = (key <= qbase + j) ? __expf(s[j] * 0.125f - m4[j]) * invd[j] : 0.f;
            float fire = 1.f / (1.f + __expf(-stp * (p - ef)));
            ms[j] += p * (lk + (1.f - lk) * fire);
        }
    }
#pragma unroll
    for (int j = 0; j < 4; ++j) {
        float t = ms[j];
        t += __shfl_xor(t, 1);
        t += __shfl_xor(t, 2);
        t += __shfl_xor(t, 4);
        t += __shfl_xor(t, 8);
        ms[j] = 1.f / (t + 1e-8f);  // invmod
    }
    // sweep 2: PV with normalized modulated probs + refractory column sums
    f32x4 accY[4] = {};
    int nchunk = qc + 1;
    for (int c = 0; c < nchunk; ++c) {
        {
            int keyl = tid >> 2;
            int d0 = (tid & 3) * 16;
            const ushort* vr = Vb + (size_t)(c * 64 + keyl) * HD + d0;
            ushort8 v0 = *(const ushort8*)vr;
            ushort8 v1 = *(const ushort8*)(vr + 8);
#pragma unroll
            for (int e = 0; e < 8; ++e) {
                vt[d0 + e][keyl] = v0[e];
                vt[d0 + 8 + e][keyl] = v1[e];
            }
        }
        __syncthreads();
#pragma unroll
        for (int sub = 0; sub < 2; ++sub) {
            int ktA = c * 4 + sub * 2;
            if (ktA <= ktmax) {
#pragma unroll
                for (int t2 = 0; t2 < 2; ++t2) {
                    int kt = ktA + t2;
                    float pv[4];
                    if (kt <= ktmax) {
                        f32x4 s = qk_tile(Kb, kt, lane, qf0, qf1);
                        int key = kt * 16 + (lane & 15);
                        float ef = eff[key];
#pragma unroll
                        for (int j = 0; j < 4; ++j) {
                            float p = (key <= qbase + j)
                                          ? __expf(s[j] * 0.125f - m4[j]) * invd[j] : 0.f;
                            float fire = 1.f / (1.f + __expf(-stp * (p - ef)));
                            pv[j] = p * (lk + (1.f - lk) * fire) * ms[j];
                        }
                        float rs_ = pv[0] + pv[1] + pv[2] + pv[3];
                        rs_ += __shfl_xor(rs_, 16);
                        rs_ += __shfl_xor(rs_, 32);
                        if (lane < 16)
                            atomicAdd(&refr_out[(size_t)b * Tc + kt * 16 + lane],
                                      rs_ * (1.f / (NH * Tc)));
                    } else {
                        pv[0] = pv[1] = pv[2] = pv[3] = 0.f;
                    }
#pragma unroll
                    for (int j = 0; j < 4; ++j)
                        plds[wave][(lane >> 4) * 4 + j][t2 * 16 + (lane & 15)] =
                            f2bf(pv[j]);
                }
                s16x8 pa = *(const s16x8*)&plds[wave][lane & 15][(lane >> 4) << 3];
#pragma unroll
                for (int nt = 0; nt < 4; ++nt) {
                    s16x8 vb_ = *(const s16x8*)&vt[nt * 16 + (lane & 15)]
                                                 [sub * 32 + ((lane >> 4) << 3)];
                    accY[nt] = __builtin_amdgcn_mfma_f32_16x16x32_bf16(pa, vb_, accY[nt], 0, 0, 0);
                }
            }
        }
        __syncthreads();
    }
#pragma unroll
    for (int nt = 0; nt < 4; ++nt)
#pragma unroll
        for (int j = 0; j < 4; ++j)
            ybuf[(size_t)(b * Tc + qbase + j) * NE + h * 64 + nt * 16 + (lane & 15)] =
                f2bf(accY[nt][j]);
}

// ---------------- launcher ----------------
extern "C" void kernel_launch(void* const* d_in, const int* in_sizes, int n_in,
                              void* d_out, int out_size, void* d_ws, size_t ws_size,
                              hipStream_t stream) {
    const float* x        = (const float*)d_in[0];
    const float* refr     = (const float*)d_in[1];
    const float* ln1_w    = (const float*)d_in[2];
    const float* ln1_b    = (const float*)d_in[3];
    const float* c_attn_w = (const float*)d_in[4];
    const float* c_attn_b = (const float*)d_in[5];
    const float* c_proj_w = (const float*)d_in[6];
    const float* c_proj_b = (const float*)d_in[7];
    const float* threshold = (const float*)d_in[8];
    const float* leak      = (const float*)d_in[9];
    const float* steepness = (const float*)d_in[10];
    const float* refractory_strength = (const float*)d_in[11];
    const float* cross_layer_weight  = (const float*)d_in[12];
    const float* ln2_w    = (const float*)d_in[13];
    const float* ln2_b    = (const float*)d_in[14];
    const float* fc_w     = (const float*)d_in[15];
    const float* fc_b     = (const float*)d_in[16];
    const float* proj_w   = (const float*)d_in[17];
    const float* proj_b   = (const float*)d_in[18];

    // workspace layout (bytes)
    char* ws = (char*)d_ws;
    ushort* hbuf   = (ushort*)(ws + 0);         // bf16 [4096][768]
    ushort* qb     = (ushort*)(ws + 6291456);   // bf16 [b,h,t,d]
    ushort* kb     = (ushort*)(ws + 12582912);
    ushort* vb     = (ushort*)(ws + 18874368);
    ushort* ybuf   = (ushort*)(ws + 25165824);  // bf16 [4096][768]
    ushort* fc_act = (ushort*)(ws + 6291456);   // bf16 [4096][3072], overlaps q/k/v/y
    float2* rowstats = (float2*)(ws + 31457280);
    float*  colsum   = (float*)(ws + 31850496);
    ushort* wt_attn  = (ushort*)(ws + 32047104);  // [2304][768]
    ushort* wt_cproj = (ushort*)(ws + 35586048);  // [768][768]
    ushort* wt_fc    = (ushort*)(ws + 36765696);  // [3072][768]
    ushort* wt_proj  = (ushort*)(ws + 41484288);  // [768][3072]

    float* xout = (float*)d_out;
    float* refr_out = xout + (size_t)BT * NE;

    hipMemsetAsync(colsum, 0, (size_t)Bc * NH * Tc * sizeof(float), stream);
    hipMemsetAsync(refr_out, 0, (size_t)Bc * Tc * sizeof(float), stream);

    wconvert<<<dim3(2304 / 32, 768 / 32), 256, 0, stream>>>(c_attn_w, wt_attn, 768, 2304);
    wconvert<<<dim3(768 / 32, 768 / 32), 256, 0, stream>>>(c_proj_w, wt_cproj, 768, 768);
    wconvert<<<dim3(3072 / 32, 768 / 32), 256, 0, stream>>>(fc_w, wt_fc, 768, 3072);
    wconvert<<<dim3(768 / 32, 3072 / 32), 256, 0, stream>>>(proj_w, wt_proj, 3072, 768);

    ln_kernel<<<BT, 256, 0, stream>>>(x, ln1_w, ln1_b, hbuf);

    mfma_gemm<2, 0, false><<<dim3(18, 32), 256, 0, stream>>>(
        hbuf, wt_attn, c_attn_b, nullptr, nullptr, nullptr, qb, kb, vb,
        BT, 3 * NE, NE);

    attn_rowstats<<<Bc * NH * 16, 256, 0, stream>>>(qb, kb, rowstats);
    attn_colsum<<<Bc * NH * 16, 256, 0, stream>>>(qb, kb, rowstats, colsum);
    attn_pv<<<Bc * NH * 16, 256, 0, stream>>>(
        qb, kb, vb, rowstats, colsum, refr, threshold, leak, steepness,
        refractory_strength, cross_layer_weight, ybuf, refr_out);

    mfma_gemm<0, 0, true><<<dim3(6, 32), 256, 0, stream>>>(
        ybuf, wt_cproj, c_proj_b, x, xout, nullptr, nullptr, nullptr, nullptr,
        BT, NE, NE);

    ln_kernel<<<BT, 256, 0, stream>>>(xout, ln2_w, ln2_b, hbuf);

    mfma_gemm<1, 1, false><<<dim3(24, 32), 256, 0, stream>>>(
        hbuf, wt_fc, fc_b, nullptr, nullptr, fc_act, nullptr, nullptr, nullptr,
        BT, 4 * NE, NE);

    mfma_gemm<0, 0, true><<<dim3(6, 32), 256, 0, stream>>>(
        fc_act, wt_proj, proj_b, xout, xout, nullptr, nullptr, nullptr, nullptr,
        BT, NE, 4 * NE);
}

// Round 3
// 373.344 us; speedup vs baseline: 9.3714x; 1.2206x over previous
//
#include <hip/hip_runtime.h>
#include <hip/hip_bf16.h>
#include <math.h>

typedef unsigned short ushort;
typedef __attribute__((ext_vector_type(8))) unsigned short ushort8;
typedef __attribute__((ext_vector_type(8))) short s16x8;
typedef __attribute__((ext_vector_type(4))) float f32x4;

constexpr int NE = 768;      // N_EMBD
constexpr int NH = 12;       // heads
constexpr int HD = 64;       // head dim
constexpr int Bc = 4;
constexpr int Tc = 1024;
constexpr int BT = Bc * Tc;  // 4096 rows

__device__ __forceinline__ ushort f2bf(float f) {
    __hip_bfloat16 h = __float2bfloat16(f);
    return *reinterpret_cast<ushort*>(&h);
}
__device__ __forceinline__ float softplus_f(float x) {
    return (x > 20.f) ? x : log1pf(__expf(x));
}
__device__ __forceinline__ float rcp_f(float x) {
#if __has_builtin(__builtin_amdgcn_rcpf)
    return __builtin_amdgcn_rcpf(x);
#else
    return 1.f / x;
#endif
}
__device__ __forceinline__ void gload16(const void* g, void* l) {
    __builtin_amdgcn_global_load_lds((const __attribute__((address_space(1))) void*)g,
                                     (__attribute__((address_space(3))) void*)l, 16, 0, 0);
}

// ---------------- LayerNorm: f32 in -> bf16 out ----------------
__global__ __launch_bounds__(256) void ln_kernel(const float* __restrict__ x,
                                                 const float* __restrict__ w,
                                                 const float* __restrict__ b,
                                                 ushort* __restrict__ out) {
    int row = blockIdx.x;
    const float* xr = x + (size_t)row * NE;
    int t = threadIdx.x;
    float v0 = xr[t], v1 = xr[t + 256], v2 = xr[t + 512];
    __shared__ float red[256], red2[256];
    red[t] = v0 + v1 + v2;
    red2[t] = v0 * v0 + v1 * v1 + v2 * v2;
    __syncthreads();
    for (int o = 128; o > 0; o >>= 1) {
        if (t < o) { red[t] += red[t + o]; red2[t] += red2[t + o]; }
        __syncthreads();
    }
    float mean = red[0] * (1.0f / NE);
    float var = red2[0] * (1.0f / NE) - mean * mean;
    float rs = rsqrtf(var + 1e-5f);
    ushort* orow = out + (size_t)row * NE;
    orow[t]       = f2bf((v0 - mean) * rs * w[t]       + b[t]);
    orow[t + 256] = f2bf((v1 - mean) * rs * w[t + 256] + b[t + 256]);
    orow[t + 512] = f2bf((v2 - mean) * rs * w[t + 512] + b[t + 512]);
}

// ---------------- weight convert: W f32 [K][N] -> Wt bf16 [N][K] ----------------
__global__ __launch_bounds__(256) void wconvert(const float* __restrict__ W,
                                                ushort* __restrict__ Wt, int K, int N) {
    __shared__ float t[32][33];
    int n0 = blockIdx.x * 32, k0 = blockIdx.y * 32;
    int c = threadIdx.x & 31, r4 = threadIdx.x >> 5;
#pragma unroll
    for (int i = 0; i < 4; ++i) {
        int r = r4 + i * 8;
        t[r][c] = W[(size_t)(k0 + r) * N + n0 + c];
    }
    __syncthreads();
#pragma unroll
    for (int i = 0; i < 4; ++i) {
        int r = r4 + i * 8;
        Wt[(size_t)(n0 + r) * K + k0 + c] = f2bf(t[c][r]);
    }
}

// ---------------- V transpose: V [bh][t][d] -> Vt [bh][d][t] (bf16) ----------------
__global__ __launch_bounds__(256) void vtrans(const ushort* __restrict__ V,
                                              ushort* __restrict__ Vt) {
    int gid = blockIdx.x * 256 + threadIdx.x;  // 48*8*128 = 49152 threads
    int tt = gid & 127;
    int rest = gid >> 7;
    int dt = rest & 7, bh = rest >> 3;
    const ushort* src = V + ((size_t)bh * Tc + tt * 8) * HD + dt * 8;
    ushort* dst = Vt + ((size_t)bh * HD + dt * 8) * Tc + tt * 8;
    ushort8 row[8];
#pragma unroll
    for (int i = 0; i < 8; ++i) row[i] = *(const ushort8*)(src + (size_t)i * HD);
#pragma unroll
    for (int e = 0; e < 8; ++e) {
        ushort8 o;
#pragma unroll
        for (int i = 0; i < 8; ++i) o[i] = row[i][e];
        *(ushort8*)(dst + (size_t)e * Tc) = o;
    }
}

// ---------------- MFMA GEMM (unchanged from round 2) ----------------
template <int OUT_MODE, int ACT, bool RES>
__global__ __launch_bounds__(256) void mfma_gemm(
    const ushort* __restrict__ A, const ushort* __restrict__ Bt,
    const float* __restrict__ bias, const float* __restrict__ residual,
    float* __restrict__ Cf, ushort* __restrict__ Cb,
    ushort* __restrict__ Qo, ushort* __restrict__ Ko, ushort* __restrict__ Vo,
    int M, int N, int K) {
    __shared__ __align__(16) ushort As[128 * 32];
    __shared__ __align__(16) ushort Bs[128 * 32];
    int tid = threadIdx.x;
    int lane = tid & 63;
    int m0 = blockIdx.y * 128, n0 = blockIdx.x * 128;
    int wave = tid >> 6;
    int wr = wave >> 1, wc = wave & 1;
    f32x4 acc[4][4] = {};
    const int sr = tid >> 2, sc8 = tid & 3;
    const ushort* ga = A + (size_t)(m0 + sr) * K + sc8 * 8;
    const ushort* gb = Bt + (size_t)(n0 + sr) * K + sc8 * 8;
    char* lA = (char*)As + (tid & 192) * 16;
    char* lB = (char*)Bs + (tid & 192) * 16;
    const char* ab = (const char*)As + ((wr << 6) + (lane & 15)) * 64 + ((lane >> 4) << 4);
    const char* bb = (const char*)Bs + ((wc << 6) + (lane & 15)) * 64 + ((lane >> 4) << 4);
    for (int k0 = 0; k0 < K; k0 += 32) {
        gload16(ga + k0, lA);
        gload16(ga + (size_t)64 * K + k0, lA + 4096);
        gload16(gb + k0, lB);
        gload16(gb + (size_t)64 * K + k0, lB + 4096);
        __syncthreads();
        s16x8 af[4], bf[4];
#pragma unroll
        for (int i = 0; i < 4; ++i) {
            af[i] = *(const s16x8*)(ab + i * 1024);
            bf[i] = *(const s16x8*)(bb + i * 1024);
        }
#pragma unroll
        for (int mi = 0; mi < 4; ++mi)
#pragma unroll
            for (int ni = 0; ni < 4; ++ni)
                acc[mi][ni] = __builtin_amdgcn_mfma_f32_16x16x32_bf16(af[mi], bf[ni], acc[mi][ni], 0, 0, 0);
        __syncthreads();
    }
#pragma unroll
    for (int mi = 0; mi < 4; ++mi) {
#pragma unroll
        for (int ni = 0; ni < 4; ++ni) {
#pragma unroll
            for (int j = 0; j < 4; ++j) {
                int row = m0 + wr * 64 + mi * 16 + (lane >> 4) * 4 + j;
                int col = n0 + wc * 64 + ni * 16 + (lane & 15);
                float v = acc[mi][ni][j] + bias[col];
                if (ACT == 1) v = 0.5f * v * (1.0f + erff(v * 0.70710678118654752f));
                if (RES) v += residual[(size_t)row * N + col];
                if (OUT_MODE == 0) {
                    Cf[(size_t)row * N + col] = v;
                } else if (OUT_MODE == 1) {
                    Cb[(size_t)row * N + col] = f2bf(v);
                } else {
                    int which = col >= 1536 ? 2 : (col >= 768 ? 1 : 0);
                    int rem = col - which * 768;
                    int h = rem >> 6, d = rem & 63;
                    int b_ = row >> 10, t_ = row & 1023;
                    ushort* dst = which == 0 ? Qo : (which == 1 ? Ko : Vo);
                    dst[((size_t)(b_ * NH + h) * Tc + t_) * HD + d] = f2bf(v);
                }
            }
        }
    }
}

// ============ Attention, balanced 2-kernel scheme ============
// Fixed-max softmax: p = exp(s - 8)/denom  (identical softmax, no max pass).
// Block = (bh, qpair): handles q-chunks {15-qp, qp}: equal work for every block.
// 8 waves: rowtile r = w&3 (16 q rows), keyhalf kh = w>>2.

// Kernel A: sweep1 row denominators (swapped QK^T), sweep2 column sums (standard).
__global__ __launch_bounds__(512) void attn_A(
    const ushort* __restrict__ Qp, const ushort* __restrict__ Kp,
    float* __restrict__ denom, float* __restrict__ colsum) {
    int bh = blockIdx.x >> 3, qp = blockIdx.x & 7;
    int tid = threadIdx.x;
    int w = tid >> 6, lane = tid & 63;
    int r = w & 3, kh = w >> 2;
    int qlane = lane & 15, g = lane >> 4;
    __shared__ float dden[2][4][16];
    __shared__ float dinv[64];
    __shared__ float cs[1024];
    for (int i = tid; i < 1024; i += 512) cs[i] = 0.f;
    const ushort* Qb = Qp + (size_t)bh * Tc * HD;
    const ushort* Kb = Kp + (size_t)bh * Tc * HD;
    __syncthreads();
    for (int ph = 0; ph < 2; ++ph) {
        int qc = ph ? qp : 15 - qp;
        int q0 = qc * 64 + r * 16;
        const ushort* qr = Qb + (size_t)(q0 + qlane) * HD + g * 8;
        s16x8 qf0 = *(const s16x8*)qr;
        s16x8 qf1 = *(const s16x8*)(qr + 32);
        int nkt = qc * 4 + r + 1;
        int kmid = (nkt + 1) >> 1;
        int klo = kh ? kmid : 0, khi = kh ? nkt : kmid;
        // sweep 1: row denominators (swapped: lane col = q)
        float dpart = 0.f;
        int q = q0 + qlane;
        for (int kt = klo; kt < khi; ++kt) {
            const ushort* kr = Kb + (size_t)(kt * 16 + qlane) * HD + g * 8;
            s16x8 kf0 = *(const s16x8*)kr;
            s16x8 kf1 = *(const s16x8*)(kr + 32);
            f32x4 z = {0.f, 0.f, 0.f, 0.f};
            z = __builtin_amdgcn_mfma_f32_16x16x32_bf16(kf0, qf0, z, 0, 0, 0);
            z = __builtin_amdgcn_mfma_f32_16x16x32_bf16(kf1, qf1, z, 0, 0, 0);
            int keyb = kt * 16 + g * 4;
#pragma unroll
            for (int j = 0; j < 4; ++j)
                if (keyb + j <= q) dpart += __expf(z[j] * 0.125f - 8.f);
        }
        dpart += __shfl_xor(dpart, 16);
        dpart += __shfl_xor(dpart, 32);
        if (lane < 16) dden[kh][r][lane] = dpart;
        __syncthreads();
        if (kh == 0 && lane < 16) {
            float d = dden[0][r][lane] + dden[1][r][lane];
            denom[(size_t)bh * Tc + q0 + lane] = d;
            dinv[r * 16 + lane] = 1.f / d;
        }
        __syncthreads();
        // sweep 2: column sums (standard: lane col = key)
        for (int kt = klo; kt < khi; ++kt) {
            const ushort* kr = Kb + (size_t)(kt * 16 + qlane) * HD + g * 8;
            s16x8 kf0 = *(const s16x8*)kr;
            s16x8 kf1 = *(const s16x8*)(kr + 32);
            f32x4 s = {0.f, 0.f, 0.f, 0.f};
            s = __builtin_amdgcn_mfma_f32_16x16x32_bf16(qf0, kf0, s, 0, 0, 0);
            s = __builtin_amdgcn_mfma_f32_16x16x32_bf16(qf1, kf1, s, 0, 0, 0);
            int key = kt * 16 + qlane;
            float cp = 0.f;
#pragma unroll
            for (int j = 0; j < 4; ++j) {
                int qq = q0 + g * 4 + j;
                if (key <= qq)
                    cp += __expf(s[j] * 0.125f - 8.f) * dinv[r * 16 + g * 4 + j];
            }
            cp += __shfl_xor(cp, 16);
            cp += __shfl_xor(cp, 32);
            if (lane < 16) atomicAdd(&cs[kt * 16 + lane], cp);
        }
        __syncthreads();
    }
    for (int i = tid; i < 1024; i += 512) {
        float v = cs[i];
        if (v != 0.f) atomicAdd(&colsum[(size_t)bh * Tc + i], v);
    }
}

// Kernel B: sweep1 modulated row sums (swapped), sweep2 PV + refractory + Y (standard).
__global__ __launch_bounds__(512) void attn_B(
    const ushort* __restrict__ Qp, const ushort* __restrict__ Kp,
    const ushort* __restrict__ Vt,
    const float* __restrict__ denom, const float* __restrict__ colsum,
    const float* __restrict__ refr_in,
    const float* __restrict__ threshold, const float* __restrict__ leak,
    const float* __restrict__ steepness, const float* __restrict__ refr_strength,
    const float* __restrict__ cross_w,
    ushort* __restrict__ ybuf, float* __restrict__ refr_out) {
    int bh = blockIdx.x >> 3, qp = blockIdx.x & 7;
    int b = bh / NH, h = bh - b * NH;
    int tid = threadIdx.x;
    int w = tid >> 6, lane = tid & 63;
    int r = w & 3, kh = w >> 2;
    int qlane = lane & 15, g = lane >> 4;
    __shared__ float eff[1024];
    __shared__ float msum[2][4][16];
    __shared__ float minv[64];
    __shared__ float rinv[64];
    __shared__ float ymrg[4][16][64];
    __shared__ __align__(16) ushort plds[8][16][40];
    float thr = fabsf(threshold[h]) * 0.1f;
    float lk = 1.f / (1.f + __expf(-leak[h]));
    float lk1m = 1.f - lk;
    float stp = softplus_f(steepness[h]);
    float rfs = softplus_f(refr_strength[h]);
    float crw = 1.f / (1.f + __expf(-cross_w[h]));
    for (int i = tid; i < 1024; i += 512)
        eff[i] = thr + rfs * (colsum[(size_t)bh * Tc + i] * (1.f / 1024.f))
                     + crw * refr_in[(size_t)b * Tc + i];
    const ushort* Qb = Qp + (size_t)bh * Tc * HD;
    const ushort* Kb = Kp + (size_t)bh * Tc * HD;
    const ushort* Vh = Vt + (size_t)bh * HD * Tc;
    __syncthreads();
    for (int ph = 0; ph < 2; ++ph) {
        int qc = ph ? qp : 15 - qp;
        int q0 = qc * 64 + r * 16;
        if (tid < 64) rinv[tid] = 1.f / denom[(size_t)bh * Tc + qc * 64 + tid];
        __syncthreads();
        const ushort* qr = Qb + (size_t)(q0 + qlane) * HD + g * 8;
        s16x8 qf0 = *(const s16x8*)qr;
        s16x8 qf1 = *(const s16x8*)(qr + 32);
        int nkt = qc * 4 + r + 1;
        int npairs = (nkt + 1) >> 1;
        int pmid = (npairs + 1) >> 1;
        int plo = kh ? pmid : 0, phi = kh ? npairs : pmid;
        int klo = plo * 2;
        int khi = (phi * 2 < nkt) ? phi * 2 : nkt;
        // sweep 1: modulated row sums (swapped)
        float mspart = 0.f;
        float di = rinv[r * 16 + qlane];
        int q = q0 + qlane;
        for (int kt = klo; kt < khi; ++kt) {
            const ushort* kr = Kb + (size_t)(kt * 16 + qlane) * HD + g * 8;
            s16x8 kf0 = *(const s16x8*)kr;
            s16x8 kf1 = *(const s16x8*)(kr + 32);
            f32x4 z = {0.f, 0.f, 0.f, 0.f};
            z = __builtin_amdgcn_mfma_f32_16x16x32_bf16(kf0, qf0, z, 0, 0, 0);
            z = __builtin_amdgcn_mfma_f32_16x16x32_bf16(kf1, qf1, z, 0, 0, 0);
            int keyb = kt * 16 + g * 4;
#pragma unroll
            for (int j = 0; j < 4; ++j) {
                int key = keyb + j;
                if (key <= q) {
                    float p = __expf(z[j] * 0.125f - 8.f) * di;
                    float fire = rcp_f(1.f + __expf(-stp * (p - eff[key])));
                    mspart += p * (lk + lk1m * fire);
                }
            }
        }
        mspart += __shfl_xor(mspart, 16);
        mspart += __shfl_xor(mspart, 32);
        if (lane < 16) msum[kh][r][lane] = mspart;
        __syncthreads();
        if (kh == 0 && lane < 16)
            minv[r * 16 + lane] = 1.f / (msum[0][r][lane] + msum[1][r][lane] + 1e-8f);
        __syncthreads();
        // sweep 2: PV (standard) in 32-key pairs + refractory column sums
        f32x4 accY[4] = {};
        for (int pr = plo; pr < phi; ++pr) {
#pragma unroll
            for (int t2 = 0; t2 < 2; ++t2) {
                int kt = pr * 2 + t2;
                if (kt < nkt) {
                    const ushort* kr = Kb + (size_t)(kt * 16 + qlane) * HD + g * 8;
                    s16x8 kf0 = *(const s16x8*)kr;
                    s16x8 kf1 = *(const s16x8*)(kr + 32);
                    f32x4 s = {0.f, 0.f, 0.f, 0.f};
                    s = __builtin_amdgcn_mfma_f32_16x16x32_bf16(qf0, kf0, s, 0, 0, 0);
                    s = __builtin_amdgcn_mfma_f32_16x16x32_bf16(qf1, kf1, s, 0, 0, 0);
                    int key = kt * 16 + qlane;
                    float ef = eff[key];
                    float rp = 0.f;
#pragma unroll
                    for (int j = 0; j < 4; ++j) {
                        int qq = q0 + g * 4 + j;
                        float pv = 0.f;
                        if (key <= qq) {
                            float p = __expf(s[j] * 0.125f - 8.f) * rinv[r * 16 + g * 4 + j];
                            float fire = rcp_f(1.f + __expf(-stp * (p - ef)));
                            pv = p * (lk + lk1m * fire) * minv[r * 16 + g * 4 + j];
                        }
                        rp += pv;
                        plds[w][g * 4 + j][t2 * 16 + qlane] = f2bf(pv);
                    }
                    rp += __shfl_xor(rp, 16);
                    rp += __shfl_xor(rp, 32);
                    if (lane < 16)
                        atomicAdd(&refr_out[(size_t)b * Tc + kt * 16 + lane],
                                  rp * (1.f / (NH * Tc)));
                } else {
#pragma unroll
                    for (int j = 0; j < 4; ++j)
                        plds[w][g * 4 + j][t2 * 16 + qlane] = 0;
                }
            }
            s16x8 pa = *(const s16x8*)&plds[w][qlane][g * 8];
#pragma unroll
            for (int dt = 0; dt < 4; ++dt) {
                const ushort* vp = Vh + (size_t)(dt * 16 + qlane) * Tc + pr * 32 + g * 8;
                s16x8 vf = *(const s16x8*)vp;
                accY[dt] = __builtin_amdgcn_mfma_f32_16x16x32_bf16(pa, vf, accY[dt], 0, 0, 0);
            }
        }
        if (kh == 1) {
#pragma unroll
            for (int dt = 0; dt < 4; ++dt)
#pragma unroll
                for (int j = 0; j < 4; ++j)
                    ymrg[r][g * 4 + j][dt * 16 + qlane] = accY[dt][j];
        }
        __syncthreads();
        if (kh == 0) {
#pragma unroll
            for (int dt = 0; dt < 4; ++dt)
#pragma unroll
                for (int j = 0; j < 4; ++j) {
                    float y = accY[dt][j] + ymrg[r][g * 4 + j][dt * 16 + qlane];
                    ybuf[(size_t)(b * Tc + q0 + g * 4 + j) * NE + h * 64 + dt * 16 + qlane] =
                        f2bf(y);
                }
        }
        __syncthreads();
    }
}

// ---------------- launcher ----------------
extern "C" void kernel_launch(void* const* d_in, const int* in_sizes, int n_in,
                              void* d_out, int out_size, void* d_ws, size_t ws_size,
                              hipStream_t stream) {
    const float* x        = (const float*)d_in[0];
    const float* refr     = (const float*)d_in[1];
    const float* ln1_w    = (const float*)d_in[2];
    const float* ln1_b    = (const float*)d_in[3];
    const float* c_attn_w = (const float*)d_in[4];
    const float* c_attn_b = (const float*)d_in[5];
    const float* c_proj_w = (const float*)d_in[6];
    const float* c_proj_b = (const float*)d_in[7];
    const float* threshold = (const float*)d_in[8];
    const float* leak      = (const float*)d_in[9];
    const float* steepness = (const float*)d_in[10];
    const float* refractory_strength = (const float*)d_in[11];
    const float* cross_layer_weight  = (const float*)d_in[12];
    const float* ln2_w    = (const float*)d_in[13];
    const float* ln2_b    = (const float*)d_in[14];
    const float* fc_w     = (const float*)d_in[15];
    const float* fc_b     = (const float*)d_in[16];
    const float* proj_w   = (const float*)d_in[17];
    const float* proj_b   = (const float*)d_in[18];

    // workspace layout (bytes)
    char* ws = (char*)d_ws;
    ushort* hbuf   = (ushort*)(ws + 0);         // bf16 [4096][768]; reused as V^T during attn
    ushort* vtg    = (ushort*)(ws + 0);         // bf16 [48][64][1024] (after qkv gemm done)
    ushort* qb     = (ushort*)(ws + 6291456);   // bf16 [b,h,t,d]
    ushort* kb     = (ushort*)(ws + 12582912);
    ushort* vb     = (ushort*)(ws + 18874368);
    ushort* ybuf   = (ushort*)(ws + 25165824);  // bf16 [4096][768]
    ushort* fc_act = (ushort*)(ws + 6291456);   // bf16 [4096][3072], overlaps q/k/v/y (post-attn)
    float*  denomb = (float*)(ws + 31457280);   // [48][1024]
    float*  colsum = (float*)(ws + 31653888);   // [48][1024]
    ushort* wt_attn  = (ushort*)(ws + 31850496);  // [2304][768]
    ushort* wt_cproj = (ushort*)(ws + 35389440);  // [768][768]
    ushort* wt_fc    = (ushort*)(ws + 36569088);  // [3072][768]
    ushort* wt_proj  = (ushort*)(ws + 41287680);  // [768][3072]

    float* xout = (float*)d_out;
    float* refr_out = xout + (size_t)BT * NE;

    hipMemsetAsync(colsum, 0, (size_t)Bc * NH * Tc * sizeof(float), stream);
    hipMemsetAsync(refr_out, 0, (size_t)Bc * Tc * sizeof(float), stream);

    wconvert<<<dim3(2304 / 32, 768 / 32), 256, 0, stream>>>(c_attn_w, wt_attn, 768, 2304);
    wconvert<<<dim3(768 / 32, 768 / 32), 256, 0, stream>>>(c_proj_w, wt_cproj, 768, 768);
    wconvert<<<dim3(3072 / 32, 768 / 32), 256, 0, stream>>>(fc_w, wt_fc, 768, 3072);
    wconvert<<<dim3(768 / 32, 3072 / 32), 256, 0, stream>>>(proj_w, wt_proj, 3072, 768);

    ln_kernel<<<BT, 256, 0, stream>>>(x, ln1_w, ln1_b, hbuf);

    mfma_gemm<2, 0, false><<<dim3(18, 32), 256, 0, stream>>>(
        hbuf, wt_attn, c_attn_b, nullptr, nullptr, nullptr, qb, kb, vb,
        BT, 3 * NE, NE);

    vtrans<<<192, 256, 0, stream>>>(vb, vtg);

    attn_A<<<Bc * NH * 8, 512, 0, stream>>>(qb, kb, denomb, colsum);

    attn_B<<<Bc * NH * 8, 512, 0, stream>>>(
        qb, kb, vtg, denomb, colsum, refr, threshold, leak, steepness,
        refractory_strength, cross_layer_weight, ybuf, refr_out);

    mfma_gemm<0, 0, true><<<dim3(6, 32), 256, 0, stream>>>(
        ybuf, wt_cproj, c_proj_b, x, xout, nullptr, nullptr, nullptr, nullptr,
        BT, NE, NE);

    ln_kernel<<<BT, 256, 0, stream>>>(xout, ln2_w, ln2_b, hbuf);

    mfma_gemm<1, 1, false><<<dim3(24, 32), 256, 0, stream>>>(
        hbuf, wt_fc, fc_b, nullptr, nullptr, fc_act, nullptr, nullptr, nullptr,
        BT, 4 * NE, NE);

    mfma_gemm<0, 0, true><<<dim3(6, 32), 256, 0, stream>>>(
        fc_act, wt_proj, proj_b, xout, xout, nullptr, nullptr, nullptr, nullptr,
        BT, NE, 4 * NE);
}

// Round 4
// 370.396 us; speedup vs baseline: 9.4460x; 1.0080x over previous
//
#include <hip/hip_runtime.h>
#include <hip/hip_bf16.h>
#include <math.h>

typedef unsigned short ushort;
typedef __attribute__((ext_vector_type(8))) unsigned short ushort8;
typedef __attribute__((ext_vector_type(8))) short s16x8;
typedef __attribute__((ext_vector_type(4))) float f32x4;

constexpr int NE = 768;      // N_EMBD
constexpr int NH = 12;       // heads
constexpr int HD = 64;       // head dim
constexpr int Bc = 4;
constexpr int Tc = 1024;
constexpr int BT = Bc * Tc;  // 4096 rows

__device__ __forceinline__ ushort f2bf(float f) {
    __hip_bfloat16 h = __float2bfloat16(f);
    return *reinterpret_cast<ushort*>(&h);
}
__device__ __forceinline__ float softplus_f(float x) {
    return (x > 20.f) ? x : log1pf(__expf(x));
}
__device__ __forceinline__ float rcp_f(float x) {
#if __has_builtin(__builtin_amdgcn_rcpf)
    return __builtin_amdgcn_rcpf(x);
#else
    return 1.f / x;
#endif
}
__device__ __forceinline__ void gload16(const void* g, void* l) {
    __builtin_amdgcn_global_load_lds((const __attribute__((address_space(1))) void*)g,
                                     (__attribute__((address_space(3))) void*)l, 16, 0, 0);
}

// ---------------- LayerNorm: f32 in -> bf16 out ----------------
__global__ __launch_bounds__(256) void ln_kernel(const float* __restrict__ x,
                                                 const float* __restrict__ w,
                                                 const float* __restrict__ b,
                                                 ushort* __restrict__ out) {
    int row = blockIdx.x;
    const float* xr = x + (size_t)row * NE;
    int t = threadIdx.x;
    float v0 = xr[t], v1 = xr[t + 256], v2 = xr[t + 512];
    __shared__ float red[256], red2[256];
    red[t] = v0 + v1 + v2;
    red2[t] = v0 * v0 + v1 * v1 + v2 * v2;
    __syncthreads();
    for (int o = 128; o > 0; o >>= 1) {
        if (t < o) { red[t] += red[t + o]; red2[t] += red2[t + o]; }
        __syncthreads();
    }
    float mean = red[0] * (1.0f / NE);
    float var = red2[0] * (1.0f / NE) - mean * mean;
    float rs = rsqrtf(var + 1e-5f);
    ushort* orow = out + (size_t)row * NE;
    orow[t]       = f2bf((v0 - mean) * rs * w[t]       + b[t]);
    orow[t + 256] = f2bf((v1 - mean) * rs * w[t + 256] + b[t + 256]);
    orow[t + 512] = f2bf((v2 - mean) * rs * w[t + 512] + b[t + 512]);
}

// ---------------- weight convert: W f32 [K][N] -> Wt bf16 [N][K] ----------------
__global__ __launch_bounds__(256) void wconvert(const float* __restrict__ W,
                                                ushort* __restrict__ Wt, int K, int N) {
    __shared__ float t[32][33];
    int n0 = blockIdx.x * 32, k0 = blockIdx.y * 32;
    int c = threadIdx.x & 31, r4 = threadIdx.x >> 5;
#pragma unroll
    for (int i = 0; i < 4; ++i) {
        int r = r4 + i * 8;
        t[r][c] = W[(size_t)(k0 + r) * N + n0 + c];
    }
    __syncthreads();
#pragma unroll
    for (int i = 0; i < 4; ++i) {
        int r = r4 + i * 8;
        Wt[(size_t)(n0 + r) * K + k0 + c] = f2bf(t[c][r]);
    }
}

// ---------------- V transpose: V [bh][t][d] -> Vt [bh][d][t] (bf16) ----------------
__global__ __launch_bounds__(256) void vtrans(const ushort* __restrict__ V,
                                              ushort* __restrict__ Vt) {
    int gid = blockIdx.x * 256 + threadIdx.x;
    int tt = gid & 127;
    int rest = gid >> 7;
    int dt = rest & 7, bh = rest >> 3;
    const ushort* src = V + ((size_t)bh * Tc + tt * 8) * HD + dt * 8;
    ushort* dst = Vt + ((size_t)bh * HD + dt * 8) * Tc + tt * 8;
    ushort8 row[8];
#pragma unroll
    for (int i = 0; i < 8; ++i) row[i] = *(const ushort8*)(src + (size_t)i * HD);
#pragma unroll
    for (int e = 0; e < 8; ++e) {
        ushort8 o;
#pragma unroll
        for (int i = 0; i < 8; ++i) o[i] = row[i][e];
        *(ushort8*)(dst + (size_t)e * Tc) = o;
    }
}

// ---------------- MFMA GEMM ----------------
template <int OUT_MODE, int ACT, bool RES>
__global__ __launch_bounds__(256) void mfma_gemm(
    const ushort* __restrict__ A, const ushort* __restrict__ Bt,
    const float* __restrict__ bias, const float* __restrict__ residual,
    float* __restrict__ Cf, ushort* __restrict__ Cb,
    ushort* __restrict__ Qo, ushort* __restrict__ Ko, ushort* __restrict__ Vo,
    int M, int N, int K) {
    __shared__ __align__(16) ushort As[128 * 32];
    __shared__ __align__(16) ushort Bs[128 * 32];
    int tid = threadIdx.x;
    int lane = tid & 63;
    int m0 = blockIdx.y * 128, n0 = blockIdx.x * 128;
    int wave = tid >> 6;
    int wr = wave >> 1, wc = wave & 1;
    f32x4 acc[4][4] = {};
    const int sr = tid >> 2, sc8 = tid & 3;
    const ushort* ga = A + (size_t)(m0 + sr) * K + sc8 * 8;
    const ushort* gb = Bt + (size_t)(n0 + sr) * K + sc8 * 8;
    char* lA = (char*)As + (tid & 192) * 16;
    char* lB = (char*)Bs + (tid & 192) * 16;
    const char* ab = (const char*)As + ((wr << 6) + (lane & 15)) * 64 + ((lane >> 4) << 4);
    const char* bb = (const char*)Bs + ((wc << 6) + (lane & 15)) * 64 + ((lane >> 4) << 4);
    for (int k0 = 0; k0 < K; k0 += 32) {
        gload16(ga + k0, lA);
        gload16(ga + (size_t)64 * K + k0, lA + 4096);
        gload16(gb + k0, lB);
        gload16(gb + (size_t)64 * K + k0, lB + 4096);
        __syncthreads();
        s16x8 af[4], bf[4];
#pragma unroll
        for (int i = 0; i < 4; ++i) {
            af[i] = *(const s16x8*)(ab + i * 1024);
            bf[i] = *(const s16x8*)(bb + i * 1024);
        }
#pragma unroll
        for (int mi = 0; mi < 4; ++mi)
#pragma unroll
            for (int ni = 0; ni < 4; ++ni)
                acc[mi][ni] = __builtin_amdgcn_mfma_f32_16x16x32_bf16(af[mi], bf[ni], acc[mi][ni], 0, 0, 0);
        __syncthreads();
    }
#pragma unroll
    for (int mi = 0; mi < 4; ++mi) {
#pragma unroll
        for (int ni = 0; ni < 4; ++ni) {
#pragma unroll
            for (int j = 0; j < 4; ++j) {
                int row = m0 + wr * 64 + mi * 16 + (lane >> 4) * 4 + j;
                int col = n0 + wc * 64 + ni * 16 + (lane & 15);
                float v = acc[mi][ni][j] + bias[col];
                if (ACT == 1) v = 0.5f * v * (1.0f + erff(v * 0.70710678118654752f));
                if (RES) v += residual[(size_t)row * N + col];
                if (OUT_MODE == 0) {
                    Cf[(size_t)row * N + col] = v;
                } else if (OUT_MODE == 1) {
                    Cb[(size_t)row * N + col] = f2bf(v);
                } else {
                    int which = col >= 1536 ? 2 : (col >= 768 ? 1 : 0);
                    int rem = col - which * 768;
                    int h = rem >> 6, d = rem & 63;
                    int b_ = row >> 10, t_ = row & 1023;
                    ushort* dst = which == 0 ? Qo : (which == 1 ? Ko : Vo);
                    dst[((size_t)(b_ * NH + h) * Tc + t_) * HD + d] = f2bf(v);
                }
            }
        }
    }
}

// ============ Attention: 3 balanced kernels, (bh,qc) grid, XCD-grouped ============
// Fixed-max softmax: p = exp(s*0.125 - 8)/denom. Block = one 64-row q-chunk.
// 8 waves: rowtile r = w&3 (16 q rows), keyhalf kh = w>>2.
// blockIdx decode bh = bid % 48 -> all 16 blocks of a head on one XCD (48 % 8 == 0).

// K1: row denominators (swapped) + column sums (standard).
__global__ __launch_bounds__(512) void attn_den_col(
    const ushort* __restrict__ Qp, const ushort* __restrict__ Kp,
    float* __restrict__ denom, float* __restrict__ colsum) {
    int bid = blockIdx.x;
    int bh = bid % 48, qc = bid / 48;
    int tid = threadIdx.x;
    int w = tid >> 6, lane = tid & 63;
    int r = w & 3, kh = w >> 2;
    int qlane = lane & 15, g = lane >> 4;
    __shared__ float dden[2][4][16];
    __shared__ float dinvL[64];
    __shared__ float cs[1024];
    int kmax = (qc + 1) * 64;
    for (int i = tid; i < kmax; i += 512) cs[i] = 0.f;
    const ushort* Qb = Qp + (size_t)bh * Tc * HD;
    const ushort* Kb = Kp + (size_t)bh * Tc * HD;
    int q0 = qc * 64 + r * 16;
    const ushort* qr = Qb + (size_t)(q0 + qlane) * HD + g * 8;
    s16x8 qf0 = *(const s16x8*)qr;
    s16x8 qf1 = *(const s16x8*)(qr + 32);
    int nkt = qc * 4 + r + 1;
    int kmid = (nkt + 1) >> 1;
    int klo = kh ? kmid : 0, khi = kh ? nkt : kmid;
    float dpart = 0.f;
    int q = q0 + qlane;
#pragma unroll 2
    for (int kt = klo; kt < khi; ++kt) {
        const ushort* kr = Kb + (size_t)(kt * 16 + qlane) * HD + g * 8;
        s16x8 kf0 = *(const s16x8*)kr;
        s16x8 kf1 = *(const s16x8*)(kr + 32);
        f32x4 z = {0.f, 0.f, 0.f, 0.f};
        z = __builtin_amdgcn_mfma_f32_16x16x32_bf16(kf0, qf0, z, 0, 0, 0);
        z = __builtin_amdgcn_mfma_f32_16x16x32_bf16(kf1, qf1, z, 0, 0, 0);
        int keyb = kt * 16 + g * 4;
#pragma unroll
        for (int j = 0; j < 4; ++j)
            if (keyb + j <= q) dpart += __expf(z[j] * 0.125f - 8.f);
    }
    dpart += __shfl_xor(dpart, 16);
    dpart += __shfl_xor(dpart, 32);
    if (lane < 16) dden[kh][r][lane] = dpart;
    __syncthreads();
    if (tid < 64) {
        float d = dden[0][tid >> 4][tid & 15] + dden[1][tid >> 4][tid & 15];
        denom[(size_t)bh * Tc + qc * 64 + tid] = d;
        dinvL[tid] = rcp_f(d);
    }
    __syncthreads();
    float dj[4];
#pragma unroll
    for (int j = 0; j < 4; ++j) dj[j] = dinvL[r * 16 + g * 4 + j];
#pragma unroll 2
    for (int kt = klo; kt < khi; ++kt) {
        const ushort* kr = Kb + (size_t)(kt * 16 + qlane) * HD + g * 8;
        s16x8 kf0 = *(const s16x8*)kr;
        s16x8 kf1 = *(const s16x8*)(kr + 32);
        f32x4 s = {0.f, 0.f, 0.f, 0.f};
        s = __builtin_amdgcn_mfma_f32_16x16x32_bf16(qf0, kf0, s, 0, 0, 0);
        s = __builtin_amdgcn_mfma_f32_16x16x32_bf16(qf1, kf1, s, 0, 0, 0);
        int key = kt * 16 + qlane;
        float cp = 0.f;
#pragma unroll
        for (int j = 0; j < 4; ++j)
            if (key <= q0 + g * 4 + j) cp += __expf(s[j] * 0.125f - 8.f) * dj[j];
        cp += __shfl_xor(cp, 16);
        cp += __shfl_xor(cp, 32);
        if (lane < 16) atomicAdd(&cs[kt * 16 + lane], cp);
    }
    __syncthreads();
    for (int i = tid; i < kmax; i += 512)
        atomicAdd(&colsum[(size_t)bh * Tc + i], cs[i]);
}

// K2: modulated row sums (swapped) -> minv; qc==15 blocks persist eff to global.
__global__ __launch_bounds__(512) void attn_modsum(
    const ushort* __restrict__ Qp, const ushort* __restrict__ Kp,
    const float* __restrict__ denom, const float* __restrict__ colsum,
    const float* __restrict__ refr_in,
    const float* __restrict__ threshold, const float* __restrict__ leak,
    const float* __restrict__ steepness, const float* __restrict__ refr_strength,
    const float* __restrict__ cross_w,
    float* __restrict__ minv_out, float* __restrict__ eff_g) {
    int bid = blockIdx.x;
    int bh = bid % 48, qc = bid / 48;
    int b = bh / NH, h = bh - b * NH;
    int tid = threadIdx.x;
    int w = tid >> 6, lane = tid & 63;
    int r = w & 3, kh = w >> 2;
    int qlane = lane & 15, g = lane >> 4;
    __shared__ float eff[1024];
    __shared__ float dinvL[64];
    __shared__ float msum[2][4][16];
    float thr = fabsf(threshold[h]) * 0.1f;
    float lk = 1.f / (1.f + __expf(-leak[h]));
    float lk1m = 1.f - lk;
    float stp = softplus_f(steepness[h]);
    float rfs = softplus_f(refr_strength[h]);
    float crw = 1.f / (1.f + __expf(-cross_w[h]));
    int kmax = (qc + 1) * 64;
    for (int i = tid; i < kmax; i += 512)
        eff[i] = thr + rfs * (colsum[(size_t)bh * Tc + i] * (1.f / 1024.f))
                     + crw * refr_in[(size_t)b * Tc + i];
    if (tid < 64) dinvL[tid] = rcp_f(denom[(size_t)bh * Tc + qc * 64 + tid]);
    __syncthreads();
    if (qc == 15)
        for (int i = tid; i < 1024; i += 512) eff_g[(size_t)bh * Tc + i] = eff[i];
    const ushort* Qb = Qp + (size_t)bh * Tc * HD;
    const ushort* Kb = Kp + (size_t)bh * Tc * HD;
    int q0 = qc * 64 + r * 16;
    const ushort* qr = Qb + (size_t)(q0 + qlane) * HD + g * 8;
    s16x8 qf0 = *(const s16x8*)qr;
    s16x8 qf1 = *(const s16x8*)(qr + 32);
    int nkt = qc * 4 + r + 1;
    int kmid = (nkt + 1) >> 1;
    int klo = kh ? kmid : 0, khi = kh ? nkt : kmid;
    float di = dinvL[r * 16 + qlane];
    float msp = 0.f;
    int q = q0 + qlane;
#pragma unroll 2
    for (int kt = klo; kt < khi; ++kt) {
        const ushort* kr = Kb + (size_t)(kt * 16 + qlane) * HD + g * 8;
        s16x8 kf0 = *(const s16x8*)kr;
        s16x8 kf1 = *(const s16x8*)(kr + 32);
        f32x4 z = {0.f, 0.f, 0.f, 0.f};
        z = __builtin_amdgcn_mfma_f32_16x16x32_bf16(kf0, qf0, z, 0, 0, 0);
        z = __builtin_amdgcn_mfma_f32_16x16x32_bf16(kf1, qf1, z, 0, 0, 0);
        int keyb = kt * 16 + g * 4;
#pragma unroll
        for (int j = 0; j < 4; ++j) {
            int key = keyb + j;
            if (key <= q) {
                float p = __expf(z[j] * 0.125f - 8.f) * di;
                float fire = rcp_f(1.f + __expf(-stp * (p - eff[key])));
                msp += p * (lk + lk1m * fire);
            }
        }
    }
    msp += __shfl_xor(msp, 16);
    msp += __shfl_xor(msp, 32);
    if (lane < 16) msum[kh][r][lane] = msp;
    __syncthreads();
    if (tid < 64)
        minv_out[(size_t)bh * Tc + qc * 64 + tid] =
            rcp_f(msum[0][tid >> 4][tid & 15] + msum[1][tid >> 4][tid & 15] + 1e-8f);
}

// K3: PV (standard, normalized via minv) + refractory + Y.
__global__ __launch_bounds__(512) void attn_pv(
    const ushort* __restrict__ Qp, const ushort* __restrict__ Kp,
    const ushort* __restrict__ Vt,
    const float* __restrict__ denom, const float* __restrict__ minv,
    const float* __restrict__ eff_g,
    const float* __restrict__ leak, const float* __restrict__ steepness,
    ushort* __restrict__ ybuf, float* __restrict__ refr_out) {
    int bid = blockIdx.x;
    int bh = bid % 48, qc = bid / 48;
    int b = bh / NH, h = bh - b * NH;
    int tid = threadIdx.x;
    int w = tid >> 6, lane = tid & 63;
    int r = w & 3, kh = w >> 2;
    int qlane = lane & 15, g = lane >> 4;
    __shared__ float eff[1024];
    __shared__ float cs[1024];
    __shared__ float dinvL[64];
    __shared__ float minvL[64];
    __shared__ float ymrg[4][16][65];
    __shared__ __align__(16) ushort plds[8][16][40];
    float lk = 1.f / (1.f + __expf(-leak[h]));
    float lk1m = 1.f - lk;
    float stp = softplus_f(steepness[h]);
    int kmax = (qc + 1) * 64;
    for (int i = tid; i < kmax; i += 512) {
        eff[i] = eff_g[(size_t)bh * Tc + i];
        cs[i] = 0.f;
    }
    if (tid < 64) {
        dinvL[tid] = rcp_f(denom[(size_t)bh * Tc + qc * 64 + tid]);
        minvL[tid] = minv[(size_t)bh * Tc + qc * 64 + tid];
    }
    __syncthreads();
    const ushort* Qb = Qp + (size_t)bh * Tc * HD;
    const ushort* Kb = Kp + (size_t)bh * Tc * HD;
    const ushort* Vh = Vt + (size_t)bh * HD * Tc;
    int q0 = qc * 64 + r * 16;
    const ushort* qr = Qb + (size_t)(q0 + qlane) * HD + g * 8;
    s16x8 qf0 = *(const s16x8*)qr;
    s16x8 qf1 = *(const s16x8*)(qr + 32);
    int nkt = qc * 4 + r + 1;
    int kmid = (nkt + 1) >> 1;
    int klo = kh ? kmid : 0, khi = kh ? nkt : kmid;
    float dj[4], mj[4];
#pragma unroll
    for (int j = 0; j < 4; ++j) {
        dj[j] = dinvL[r * 16 + g * 4 + j];
        mj[j] = minvL[r * 16 + g * 4 + j];
    }
    f32x4 accY[4] = {};
    for (int kt0 = klo; kt0 < khi; kt0 += 2) {
#pragma unroll
        for (int t2 = 0; t2 < 2; ++t2) {
            int kt = kt0 + t2;
            if (kt < khi) {
                const ushort* kr = Kb + (size_t)(kt * 16 + qlane) * HD + g * 8;
                s16x8 kf0 = *(const s16x8*)kr;
                s16x8 kf1 = *(const s16x8*)(kr + 32);
                f32x4 s = {0.f, 0.f, 0.f, 0.f};
                s = __builtin_amdgcn_mfma_f32_16x16x32_bf16(qf0, kf0, s, 0, 0, 0);
                s = __builtin_amdgcn_mfma_f32_16x16x32_bf16(qf1, kf1, s, 0, 0, 0);
                int key = kt * 16 + qlane;
                float ef = eff[key];
                float rp = 0.f;
#pragma unroll
                for (int j = 0; j < 4; ++j) {
                    float pv = 0.f;
                    if (key <= q0 + g * 4 + j) {
                        float p = __expf(s[j] * 0.125f - 8.f) * dj[j];
                        float fire = rcp_f(1.f + __expf(-stp * (p - ef)));
                        pv = p * (lk + lk1m * fire) * mj[j];
                    }
                    rp += pv;
                    plds[w][g * 4 + j][t2 * 16 + qlane] = f2bf(pv);
                }
                rp += __shfl_xor(rp, 16);
                rp += __shfl_xor(rp, 32);
                if (lane < 16) atomicAdd(&cs[kt * 16 + lane], rp);
            } else {
#pragma unroll
                for (int j = 0; j < 4; ++j)
                    plds[w][g * 4 + j][t2 * 16 + qlane] = 0;
            }
        }
        s16x8 pa = *(const s16x8*)&plds[w][qlane][g * 8];
#pragma unroll
        for (int dt = 0; dt < 4; ++dt) {
            const ushort* vp = Vh + (size_t)(dt * 16 + qlane) * Tc + kt0 * 16 + g * 8;
            s16x8 vf = *(const s16x8*)vp;
            accY[dt] = __builtin_amdgcn_mfma_f32_16x16x32_bf16(pa, vf, accY[dt], 0, 0, 0);
        }
    }
    if (kh == 1) {
#pragma unroll
        for (int dt = 0; dt < 4; ++dt)
#pragma unroll
            for (int j = 0; j < 4; ++j)
                ymrg[r][g * 4 + j][dt * 16 + qlane] = accY[dt][j];
    }
    __syncthreads();
    if (kh == 0) {
#pragma unroll
        for (int dt = 0; dt < 4; ++dt)
#pragma unroll
            for (int j = 0; j < 4; ++j) {
                float y = accY[dt][j] + ymrg[r][g * 4 + j][dt * 16 + qlane];
                ybuf[(size_t)(b * Tc + q0 + g * 4 + j) * NE + h * 64 + dt * 16 + qlane] =
                    f2bf(y);
            }
    }
    for (int i = tid; i < kmax; i += 512)
        atomicAdd(&refr_out[(size_t)b * Tc + i], cs[i] * (1.f / (NH * Tc)));
}

// ---------------- launcher ----------------
extern "C" void kernel_launch(void* const* d_in, const int* in_sizes, int n_in,
                              void* d_out, int out_size, void* d_ws, size_t ws_size,
                              hipStream_t stream) {
    const float* x        = (const float*)d_in[0];
    const float* refr     = (const float*)d_in[1];
    const float* ln1_w    = (const float*)d_in[2];
    const float* ln1_b    = (const float*)d_in[3];
    const float* c_attn_w = (const float*)d_in[4];
    const float* c_attn_b = (const float*)d_in[5];
    const float* c_proj_w = (const float*)d_in[6];
    const float* c_proj_b = (const float*)d_in[7];
    const float* threshold = (const float*)d_in[8];
    const float* leak      = (const float*)d_in[9];
    const float* steepness = (const float*)d_in[10];
    const float* refractory_strength = (const float*)d_in[11];
    const float* cross_layer_weight  = (const float*)d_in[12];
    const float* ln2_w    = (const float*)d_in[13];
    const float* ln2_b    = (const float*)d_in[14];
    const float* fc_w     = (const float*)d_in[15];
    const float* fc_b     = (const float*)d_in[16];
    const float* proj_w   = (const float*)d_in[17];
    const float* proj_b   = (const float*)d_in[18];

    // workspace layout (bytes)
    char* ws = (char*)d_ws;
    ushort* hbuf   = (ushort*)(ws + 0);         // bf16 [4096][768]; reused as V^T in attn
    ushort* vtg    = (ushort*)(ws + 0);
    ushort* qb     = (ushort*)(ws + 6291456);
    ushort* kb     = (ushort*)(ws + 12582912);
    ushort* vb     = (ushort*)(ws + 18874368);
    ushort* ybuf   = (ushort*)(ws + 25165824);
    ushort* fc_act = (ushort*)(ws + 6291456);   // overlaps q/k/v/y (post-attn)
    float*  denomb = (float*)(ws + 31457280);   // [48][1024]
    float*  colsum = (float*)(ws + 31653888);   // [48][1024]
    ushort* wt_attn  = (ushort*)(ws + 31850496);
    ushort* wt_cproj = (ushort*)(ws + 35389440);
    ushort* wt_fc    = (ushort*)(ws + 36569088);
    ushort* wt_proj  = (ushort*)(ws + 41287680);
    float*  minvb    = (float*)(ws + 46006272); // [48][1024]
    float*  effg     = (float*)(ws + 46202880); // [48][1024]

    float* xout = (float*)d_out;
    float* refr_out = xout + (size_t)BT * NE;

    hipMemsetAsync(colsum, 0, (size_t)Bc * NH * Tc * sizeof(float), stream);
    hipMemsetAsync(refr_out, 0, (size_t)Bc * Tc * sizeof(float), stream);

    wconvert<<<dim3(2304 / 32, 768 / 32), 256, 0, stream>>>(c_attn_w, wt_attn, 768, 2304);
    wconvert<<<dim3(768 / 32, 768 / 32), 256, 0, stream>>>(c_proj_w, wt_cproj, 768, 768);
    wconvert<<<dim3(3072 / 32, 768 / 32), 256, 0, stream>>>(fc_w, wt_fc, 768, 3072);
    wconvert<<<dim3(768 / 32, 3072 / 32), 256, 0, stream>>>(proj_w, wt_proj, 3072, 768);

    ln_kernel<<<BT, 256, 0, stream>>>(x, ln1_w, ln1_b, hbuf);

    mfma_gemm<2, 0, false><<<dim3(18, 32), 256, 0, stream>>>(
        hbuf, wt_attn, c_attn_b, nullptr, nullptr, nullptr, qb, kb, vb,
        BT, 3 * NE, NE);

    vtrans<<<192, 256, 0, stream>>>(vb, vtg);

    attn_den_col<<<48 * 16, 512, 0, stream>>>(qb, kb, denomb, colsum);

    attn_modsum<<<48 * 16, 512, 0, stream>>>(
        qb, kb, denomb, colsum, refr, threshold, leak, steepness,
        refractory_strength, cross_layer_weight, minvb, effg);

    attn_pv<<<48 * 16, 512, 0, stream>>>(
        qb, kb, vtg, denomb, minvb, effg, leak, steepness, ybuf, refr_out);

    mfma_gemm<0, 0, true><<<dim3(6, 32), 256, 0, stream>>>(
        ybuf, wt_cproj, c_proj_b, x, xout, nullptr, nullptr, nullptr, nullptr,
        BT, NE, NE);

    ln_kernel<<<BT, 256, 0, stream>>>(xout, ln2_w, ln2_b, hbuf);

    mfma_gemm<1, 1, false><<<dim3(24, 32), 256, 0, stream>>>(
        hbuf, wt_fc, fc_b, nullptr, nullptr, fc_act, nullptr, nullptr, nullptr,
        BT, 4 * NE, NE);

    mfma_gemm<0, 0, true><<<dim3(6, 32), 256, 0, stream>>>(
        fc_act, wt_proj, proj_b, xout, xout, nullptr, nullptr, nullptr, nullptr,
        BT, NE, 4 * NE);
}

// Round 5
// 315.984 us; speedup vs baseline: 11.0726x; 1.1722x over previous
//
#include <hip/hip_runtime.h>
#include <hip/hip_bf16.h>
#include <math.h>

typedef unsigned short ushort;
typedef __attribute__((ext_vector_type(8))) unsigned short ushort8;
typedef __attribute__((ext_vector_type(8))) short s16x8;
typedef __attribute__((ext_vector_type(4))) float f32x4;

constexpr int NE = 768;      // N_EMBD
constexpr int NH = 12;       // heads
constexpr int HD = 64;       // head dim
constexpr int Bc = 4;
constexpr int Tc = 1024;
constexpr int BT = Bc * Tc;  // 4096 rows

__device__ __forceinline__ ushort f2bf(float f) {
    __hip_bfloat16 h = __float2bfloat16(f);
    return *reinterpret_cast<ushort*>(&h);
}
__device__ __forceinline__ float softplus_f(float x) {
    return (x > 20.f) ? x : log1pf(__expf(x));
}
__device__ __forceinline__ float rcp_f(float x) {
#if __has_builtin(__builtin_amdgcn_rcpf)
    return __builtin_amdgcn_rcpf(x);
#else
    return 1.f / x;
#endif
}
__device__ __forceinline__ void gload16(const void* g, void* l) {
    __builtin_amdgcn_global_load_lds((const __attribute__((address_space(1))) void*)g,
                                     (__attribute__((address_space(3))) void*)l, 16, 0, 0);
}

// ---------------- LayerNorm: f32 in -> bf16 out ----------------
__global__ __launch_bounds__(256) void ln_kernel(const float* __restrict__ x,
                                                 const float* __restrict__ w,
                                                 const float* __restrict__ b,
                                                 ushort* __restrict__ out) {
    int row = blockIdx.x;
    const float* xr = x + (size_t)row * NE;
    int t = threadIdx.x;
    float v0 = xr[t], v1 = xr[t + 256], v2 = xr[t + 512];
    __shared__ float red[256], red2[256];
    red[t] = v0 + v1 + v2;
    red2[t] = v0 * v0 + v1 * v1 + v2 * v2;
    __syncthreads();
    for (int o = 128; o > 0; o >>= 1) {
        if (t < o) { red[t] += red[t + o]; red2[t] += red2[t + o]; }
        __syncthreads();
    }
    float mean = red[0] * (1.0f / NE);
    float var = red2[0] * (1.0f / NE) - mean * mean;
    float rs = rsqrtf(var + 1e-5f);
    ushort* orow = out + (size_t)row * NE;
    orow[t]       = f2bf((v0 - mean) * rs * w[t]       + b[t]);
    orow[t + 256] = f2bf((v1 - mean) * rs * w[t + 256] + b[t + 256]);
    orow[t + 512] = f2bf((v2 - mean) * rs * w[t + 512] + b[t + 512]);
}

// ---------------- weight convert: W f32 [K][N] -> Wt bf16 [N][K] ----------------
__global__ __launch_bounds__(256) void wconvert(const float* __restrict__ W,
                                                ushort* __restrict__ Wt, int K, int N) {
    __shared__ float t[32][33];
    int n0 = blockIdx.x * 32, k0 = blockIdx.y * 32;
    int c = threadIdx.x & 31, r4 = threadIdx.x >> 5;
#pragma unroll
    for (int i = 0; i < 4; ++i) {
        int r = r4 + i * 8;
        t[r][c] = W[(size_t)(k0 + r) * N + n0 + c];
    }
    __syncthreads();
#pragma unroll
    for (int i = 0; i < 4; ++i) {
        int r = r4 + i * 8;
        Wt[(size_t)(n0 + r) * K + k0 + c] = f2bf(t[c][r]);
    }
}

// ---------------- MFMA GEMM: C[M][N] = A(bf16 [M][K]) @ Bt(bf16 [N][K])^T ----------------
// BM in {128, 64}; BN = 128; BK = 64; 4 waves.
// LDS layout: row-major [row][64] bf16 (128 B/row), 16B chunks XOR-swizzled by (row&7)
// (gload dest linear; swizzle applied on the global SOURCE address + ds_read address).
// OUT_MODE: 0 = f32 to Cf, 1 = bf16 to Cb, 2 = qkv scatter (V written transposed).
template <int BM, int OUT_MODE, int ACT, bool RES>
__global__ __launch_bounds__(256) void mfma_gemm(
    const ushort* __restrict__ A, const ushort* __restrict__ Bt,
    const float* __restrict__ bias, const float* __restrict__ residual,
    float* __restrict__ Cf, ushort* __restrict__ Cb,
    ushort* __restrict__ Qo, ushort* __restrict__ Ko, ushort* __restrict__ Vo,
    int M, int N, int K, int NBX) {
    constexpr int MF = 4;
    constexpr int NF = (BM == 128) ? 4 : 2;
    constexpr int APASS = BM / 32;
    __shared__ __align__(16) ushort As[BM * 64];
    __shared__ __align__(16) ushort Bs[128 * 64];
    int tid = threadIdx.x;
    int lane = tid & 63;
    // chunked XCD swizzle (grid %8 == 0)
    int nb = gridDim.x;
    int lin = blockIdx.x;
    int nl = (lin & 7) * (nb >> 3) + (lin >> 3);
    int bx = nl % NBX, by = nl / NBX;
    int m0 = by * BM, n0 = bx * 128;
    int wave = tid >> 6;
    int wr = (BM == 128) ? (wave >> 1) : 0;
    int wc = (BM == 128) ? (wave & 1) : wave;
    f32x4 acc[MF][NF] = {};
    // staging: pass p covers rows p*32 + (tid>>3); source col-chunk pre-swizzled
    int srow = tid >> 3;
    int scol = (tid & 7) ^ (srow & 7);
    const ushort* ga = A + (size_t)(m0 + srow) * K + scol * 8;
    const ushort* gb = Bt + (size_t)(n0 + srow) * K + scol * 8;
    char* lA = (char*)As + tid * 16;
    char* lB = (char*)Bs + tid * 16;
    // fragment bases
    int fr = lane & 15, g = lane >> 4;
    unsigned swz = (unsigned)((fr & 7) << 4);
    const char* abase = (const char*)As + (wr * 64 + fr) * 128;
    const char* bbase = (const char*)Bs + (wc * (NF * 16) + fr) * 128;
    for (int k0 = 0; k0 < K; k0 += 64) {
#pragma unroll
        for (int p = 0; p < APASS; ++p)
            gload16(ga + (size_t)(p * 32) * K + k0, lA + p * 4096);
#pragma unroll
        for (int p = 0; p < 4; ++p)
            gload16(gb + (size_t)(p * 32) * K + k0, lB + p * 4096);
        __syncthreads();
#pragma unroll
        for (int ks = 0; ks < 2; ++ks) {
            unsigned o = ((unsigned)(g * 16 + ks * 64)) ^ swz;
            s16x8 af[MF], bf[NF];
#pragma unroll
            for (int i = 0; i < MF; ++i) af[i] = *(const s16x8*)(abase + i * 2048 + o);
#pragma unroll
            for (int i = 0; i < NF; ++i) bf[i] = *(const s16x8*)(bbase + i * 2048 + o);
#pragma unroll
            for (int mi = 0; mi < MF; ++mi)
#pragma unroll
                for (int ni = 0; ni < NF; ++ni)
                    acc[mi][ni] = __builtin_amdgcn_mfma_f32_16x16x32_bf16(af[mi], bf[ni], acc[mi][ni], 0, 0, 0);
        }
        __syncthreads();
    }
#pragma unroll
    for (int mi = 0; mi < MF; ++mi) {
#pragma unroll
        for (int ni = 0; ni < NF; ++ni) {
#pragma unroll
            for (int j = 0; j < 4; ++j) {
                int row = m0 + wr * 64 + mi * 16 + g * 4 + j;
                int col = n0 + wc * (NF * 16) + ni * 16 + fr;
                float v = acc[mi][ni][j] + bias[col];
                if (ACT == 1) v = 0.5f * v * (1.0f + erff(v * 0.70710678118654752f));
                if (RES) v += residual[(size_t)row * N + col];
                if (OUT_MODE == 0) {
                    Cf[(size_t)row * N + col] = v;
                } else if (OUT_MODE == 1) {
                    Cb[(size_t)row * N + col] = f2bf(v);
                } else {
                    int which = col >= 1536 ? 2 : (col >= 768 ? 1 : 0);
                    int rem = col - which * 768;
                    int hh = rem >> 6, d = rem & 63;
                    int b_ = row >> 10, t_ = row & 1023;
                    if (which == 2)
                        Vo[((size_t)(b_ * NH + hh) * HD + d) * Tc + t_] = f2bf(v);
                    else {
                        ushort* dst = which == 0 ? Qo : Ko;
                        dst[((size_t)(b_ * NH + hh) * Tc + t_) * HD + d] = f2bf(v);
                    }
                }
            }
        }
    }
}

// ============ Attention: 2 balanced kernels, (bh,qc) grid, XCD-grouped ============
// Fixed-max softmax: p = exp(s*0.125 - 8)/denom. Block = one 64-row q-chunk.
// 8 waves: rowtile r = w&3 (16 q rows), keyhalf kh = w>>2. bh = bid % 48 (48%8==0).

// K1: row denominators (swapped) + column sums (standard).
__global__ __launch_bounds__(512) void attn_den_col(
    const ushort* __restrict__ Qp, const ushort* __restrict__ Kp,
    float* __restrict__ denom, float* __restrict__ colsum) {
    int bid = blockIdx.x;
    int bh = bid % 48, qc = bid / 48;
    int tid = threadIdx.x;
    int w = tid >> 6, lane = tid & 63;
    int r = w & 3, kh = w >> 2;
    int qlane = lane & 15, g = lane >> 4;
    __shared__ float dden[2][4][16];
    __shared__ float dinvL[64];
    __shared__ float cs[1024];
    int kmax = (qc + 1) * 64;
    for (int i = tid; i < kmax; i += 512) cs[i] = 0.f;
    const ushort* Qb = Qp + (size_t)bh * Tc * HD;
    const ushort* Kb = Kp + (size_t)bh * Tc * HD;
    int q0 = qc * 64 + r * 16;
    const ushort* qr = Qb + (size_t)(q0 + qlane) * HD + g * 8;
    s16x8 qf0 = *(const s16x8*)qr;
    s16x8 qf1 = *(const s16x8*)(qr + 32);
    int nkt = qc * 4 + r + 1;
    int kmid = (nkt + 1) >> 1;
    int klo = kh ? kmid : 0, khi = kh ? nkt : kmid;
    float dpart = 0.f;
    int q = q0 + qlane;
#pragma unroll 2
    for (int kt = klo; kt < khi; ++kt) {
        const ushort* kr = Kb + (size_t)(kt * 16 + qlane) * HD + g * 8;
        s16x8 kf0 = *(const s16x8*)kr;
        s16x8 kf1 = *(const s16x8*)(kr + 32);
        f32x4 z = {0.f, 0.f, 0.f, 0.f};
        z = __builtin_amdgcn_mfma_f32_16x16x32_bf16(kf0, qf0, z, 0, 0, 0);
        z = __builtin_amdgcn_mfma_f32_16x16x32_bf16(kf1, qf1, z, 0, 0, 0);
        int keyb = kt * 16 + g * 4;
#pragma unroll
        for (int j = 0; j < 4; ++j)
            if (keyb + j <= q) dpart += __expf(z[j] * 0.125f - 8.f);
    }
    dpart += __shfl_xor(dpart, 16);
    dpart += __shfl_xor(dpart, 32);
    if (lane < 16) dden[kh][r][lane] = dpart;
    __syncthreads();
    if (tid < 64) {
        float d = dden[0][tid >> 4][tid & 15] + dden[1][tid >> 4][tid & 15];
        denom[(size_t)bh * Tc + qc * 64 + tid] = d;
        dinvL[tid] = rcp_f(d);
    }
    __syncthreads();
    float dj[4];
#pragma unroll
    for (int j = 0; j < 4; ++j) dj[j] = dinvL[r * 16 + g * 4 + j];
#pragma unroll 2
    for (int kt = klo; kt < khi; ++kt) {
        const ushort* kr = Kb + (size_t)(kt * 16 + qlane) * HD + g * 8;
        s16x8 kf0 = *(const s16x8*)kr;
        s16x8 kf1 = *(const s16x8*)(kr + 32);
        f32x4 s = {0.f, 0.f, 0.f, 0.f};
        s = __builtin_amdgcn_mfma_f32_16x16x32_bf16(qf0, kf0, s, 0, 0, 0);
        s = __builtin_amdgcn_mfma_f32_16x16x32_bf16(qf1, kf1, s, 0, 0, 0);
        int key = kt * 16 + qlane;
        float cp = 0.f;
#pragma unroll
        for (int j = 0; j < 4; ++j)
            if (key <= q0 + g * 4 + j) cp += __expf(s[j] * 0.125f - 8.f) * dj[j];
        cp += __shfl_xor(cp, 16);
        cp += __shfl_xor(cp, 32);
        if (lane < 16) atomicAdd(&cs[kt * 16 + lane], cp);
    }
    __syncthreads();
    for (int i = tid; i < kmax; i += 512)
        atomicAdd(&colsum[(size_t)bh * Tc + i], cs[i]);
}

// K2 (fused): modulated row sums (swapped) -> minv in LDS; then PV + refractory + Y.
__global__ __launch_bounds__(512) void attn_modpv(
    const ushort* __restrict__ Qp, const ushort* __restrict__ Kp,
    const ushort* __restrict__ Vt,
    const float* __restrict__ denom, const float* __restrict__ colsum,
    const float* __restrict__ refr_in,
    const float* __restrict__ threshold, const float* __restrict__ leak,
    const float* __restrict__ steepness, const float* __restrict__ refr_strength,
    const float* __restrict__ cross_w,
    ushort* __restrict__ ybuf, float* __restrict__ refr_out) {
    int bid = blockIdx.x;
    int bh = bid % 48, qc = bid / 48;
    int b = bh / NH, h = bh - b * NH;
    int tid = threadIdx.x;
    int w = tid >> 6, lane = tid & 63;
    int r = w & 3, kh = w >> 2;
    int qlane = lane & 15, g = lane >> 4;
    __shared__ float eff[1024];
    __shared__ float cs[1024];
    __shared__ float dinvL[64];
    __shared__ float msum[2][4][16];
    __shared__ float minvL[64];
    __shared__ float ymrg[4][16][65];
    __shared__ __align__(16) ushort plds[8][16][40];
    float thr = fabsf(threshold[h]) * 0.1f;
    float lk = 1.f / (1.f + __expf(-leak[h]));
    float lk1m = 1.f - lk;
    float stp = softplus_f(steepness[h]);
    float rfs = softplus_f(refr_strength[h]);
    float crw = 1.f / (1.f + __expf(-cross_w[h]));
    int kmax = (qc + 1) * 64;
    for (int i = tid; i < kmax; i += 512) {
        eff[i] = thr + rfs * (colsum[(size_t)bh * Tc + i] * (1.f / 1024.f))
                     + crw * refr_in[(size_t)b * Tc + i];
        cs[i] = 0.f;
    }
    if (tid < 64) dinvL[tid] = rcp_f(denom[(size_t)bh * Tc + qc * 64 + tid]);
    __syncthreads();
    const ushort* Qb = Qp + (size_t)bh * Tc * HD;
    const ushort* Kb = Kp + (size_t)bh * Tc * HD;
    const ushort* Vh = Vt + (size_t)bh * HD * Tc;
    int q0 = qc * 64 + r * 16;
    const ushort* qr = Qb + (size_t)(q0 + qlane) * HD + g * 8;
    s16x8 qf0 = *(const s16x8*)qr;
    s16x8 qf1 = *(const s16x8*)(qr + 32);
    int nkt = qc * 4 + r + 1;
    int kmid = (nkt + 1) >> 1;
    int klo = kh ? kmid : 0, khi = kh ? nkt : kmid;
    // sweep 1: modulated row sums (swapped)
    float di = dinvL[r * 16 + qlane];
    float msp = 0.f;
    int q = q0 + qlane;
#pragma unroll 2
    for (int kt = klo; kt < khi; ++kt) {
        const ushort* kr = Kb + (size_t)(kt * 16 + qlane) * HD + g * 8;
        s16x8 kf0 = *(const s16x8*)kr;
        s16x8 kf1 = *(const s16x8*)(kr + 32);
        f32x4 z = {0.f, 0.f, 0.f, 0.f};
        z = __builtin_amdgcn_mfma_f32_16x16x32_bf16(kf0, qf0, z, 0, 0, 0);
        z = __builtin_amdgcn_mfma_f32_16x16x32_bf16(kf1, qf1, z, 0, 0, 0);
        int keyb = kt * 16 + g * 4;
#pragma unroll
        for (int j = 0; j < 4; ++j) {
            int key = keyb + j;
            if (key <= q) {
                float p = __expf(z[j] * 0.125f - 8.f) * di;
                float fire = rcp_f(1.f + __expf(-stp * (p - eff[key])));
                msp += p * (lk + lk1m * fire);
            }
        }
    }
    msp += __shfl_xor(msp, 16);
    msp += __shfl_xor(msp, 32);
    if (lane < 16) msum[kh][r][lane] = msp;
    __syncthreads();
    if (tid < 64)
        minvL[tid] = rcp_f(msum[0][tid >> 4][tid & 15] + msum[1][tid >> 4][tid & 15] + 1e-8f);
    __syncthreads();
    // sweep 2: PV (standard) + refractory column sums
    float dj[4], mj[4];
#pragma unroll
    for (int j = 0; j < 4; ++j) {
        dj[j] = dinvL[r * 16 + g * 4 + j];
        mj[j] = minvL[r * 16 + g * 4 + j];
    }
    f32x4 accY[4] = {};
    for (int kt0 = klo; kt0 < khi; kt0 += 2) {
#pragma unroll
        for (int t2 = 0; t2 < 2; ++t2) {
            int kt = kt0 + t2;
            if (kt < khi) {
                const ushort* kr = Kb + (size_t)(kt * 16 + qlane) * HD + g * 8;
                s16x8 kf0 = *(const s16x8*)kr;
                s16x8 kf1 = *(const s16x8*)(kr + 32);
                f32x4 s = {0.f, 0.f, 0.f, 0.f};
                s = __builtin_amdgcn_mfma_f32_16x16x32_bf16(qf0, kf0, s, 0, 0, 0);
                s = __builtin_amdgcn_mfma_f32_16x16x32_bf16(qf1, kf1, s, 0, 0, 0);
                int key = kt * 16 + qlane;
                float ef = eff[key];
                float rp = 0.f;
#pragma unroll
                for (int j = 0; j < 4; ++j) {
                    float pv = 0.f;
                    if (key <= q0 + g * 4 + j) {
                        float p = __expf(s[j] * 0.125f - 8.f) * dj[j];
                        float fire = rcp_f(1.f + __expf(-stp * (p - ef)));
                        pv = p * (lk + lk1m * fire) * mj[j];
                    }
                    rp += pv;
                    plds[w][g * 4 + j][t2 * 16 + qlane] = f2bf(pv);
                }
                rp += __shfl_xor(rp, 16);
                rp += __shfl_xor(rp, 32);
                if (lane < 16) atomicAdd(&cs[kt * 16 + lane], rp);
            } else {
#pragma unroll
                for (int j = 0; j < 4; ++j)
                    plds[w][g * 4 + j][t2 * 16 + qlane] = 0;
            }
        }
        s16x8 pa = *(const s16x8*)&plds[w][qlane][g * 8];
#pragma unroll
        for (int dt = 0; dt < 4; ++dt) {
            const ushort* vp = Vh + (size_t)(dt * 16 + qlane) * Tc + kt0 * 16 + g * 8;
            s16x8 vf = *(const s16x8*)vp;
            accY[dt] = __builtin_amdgcn_mfma_f32_16x16x32_bf16(pa, vf, accY[dt], 0, 0, 0);
        }
    }
    if (kh == 1) {
#pragma unroll
        for (int dt = 0; dt < 4; ++dt)
#pragma unroll
            for (int j = 0; j < 4; ++j)
                ymrg[r][g * 4 + j][dt * 16 + qlane] = accY[dt][j];
    }
    __syncthreads();
    if (kh == 0) {
#pragma unroll
        for (int dt = 0; dt < 4; ++dt)
#pragma unroll
            for (int j = 0; j < 4; ++j) {
                float y = accY[dt][j] + ymrg[r][g * 4 + j][dt * 16 + qlane];
                ybuf[(size_t)(b * Tc + q0 + g * 4 + j) * NE + h * 64 + dt * 16 + qlane] =
                    f2bf(y);
            }
    }
    for (int i = tid; i < kmax; i += 512)
        atomicAdd(&refr_out[(size_t)b * Tc + i], cs[i] * (1.f / (NH * Tc)));
}

// ---------------- launcher ----------------
extern "C" void kernel_launch(void* const* d_in, const int* in_sizes, int n_in,
                              void* d_out, int out_size, void* d_ws, size_t ws_size,
                              hipStream_t stream) {
    const float* x        = (const float*)d_in[0];
    const float* refr     = (const float*)d_in[1];
    const float* ln1_w    = (const float*)d_in[2];
    const float* ln1_b    = (const float*)d_in[3];
    const float* c_attn_w = (const float*)d_in[4];
    const float* c_attn_b = (const float*)d_in[5];
    const float* c_proj_w = (const float*)d_in[6];
    const float* c_proj_b = (const float*)d_in[7];
    const float* threshold = (const float*)d_in[8];
    const float* leak      = (const float*)d_in[9];
    const float* steepness = (const float*)d_in[10];
    const float* refractory_strength = (const float*)d_in[11];
    const float* cross_layer_weight  = (const float*)d_in[12];
    const float* ln2_w    = (const float*)d_in[13];
    const float* ln2_b    = (const float*)d_in[14];
    const float* fc_w     = (const float*)d_in[15];
    const float* fc_b     = (const float*)d_in[16];
    const float* proj_w   = (const float*)d_in[17];
    const float* proj_b   = (const float*)d_in[18];

    // workspace layout (bytes)
    char* ws = (char*)d_ws;
    ushort* hbuf   = (ushort*)(ws + 0);         // bf16 [4096][768]
    ushort* qb     = (ushort*)(ws + 6291456);   // bf16 [b,h,t,d]
    ushort* kb     = (ushort*)(ws + 12582912);  // bf16 [b,h,t,d]
    ushort* vtg    = (ushort*)(ws + 18874368);  // bf16 V^T [b,h,d,t]
    ushort* ybuf   = (ushort*)(ws + 25165824);  // bf16 [4096][768]
    ushort* fc_act = (ushort*)(ws + 6291456);   // bf16 [4096][3072], overlaps q/k/v/y (post-attn)
    float*  denomb = (float*)(ws + 31457280);   // [48][1024]
    float*  colsum = (float*)(ws + 31653888);   // [48][1024]
    ushort* wt_attn  = (ushort*)(ws + 31850496);
    ushort* wt_cproj = (ushort*)(ws + 35389440);
    ushort* wt_fc    = (ushort*)(ws + 36569088);
    ushort* wt_proj  = (ushort*)(ws + 41287680);

    float* xout = (float*)d_out;
    float* refr_out = xout + (size_t)BT * NE;

    hipMemsetAsync(colsum, 0, (size_t)Bc * NH * Tc * sizeof(float), stream);
    hipMemsetAsync(refr_out, 0, (size_t)Bc * Tc * sizeof(float), stream);

    wconvert<<<dim3(2304 / 32, 768 / 32), 256, 0, stream>>>(c_attn_w, wt_attn, 768, 2304);
    wconvert<<<dim3(768 / 32, 768 / 32), 256, 0, stream>>>(c_proj_w, wt_cproj, 768, 768);
    wconvert<<<dim3(3072 / 32, 768 / 32), 256, 0, stream>>>(fc_w, wt_fc, 768, 3072);
    wconvert<<<dim3(768 / 32, 3072 / 32), 256, 0, stream>>>(proj_w, wt_proj, 3072, 768);

    ln_kernel<<<BT, 256, 0, stream>>>(x, ln1_w, ln1_b, hbuf);

    // qkv: M=4096 N=2304 K=768, 128-tiles -> 18*32 = 576 blocks
    mfma_gemm<128, 2, 0, false><<<576, 256, 0, stream>>>(
        hbuf, wt_attn, c_attn_b, nullptr, nullptr, nullptr, qb, kb, vtg,
        BT, 3 * NE, NE, 18);

    attn_den_col<<<48 * 16, 512, 0, stream>>>(qb, kb, denomb, colsum);

    attn_modpv<<<48 * 16, 512, 0, stream>>>(
        qb, kb, vtg, denomb, colsum, refr, threshold, leak, steepness,
        refractory_strength, cross_layer_weight, ybuf, refr_out);

    // c_proj: M=4096 N=768 K=768, 64x128 tiles -> 6*64 = 384 blocks
    mfma_gemm<64, 0, 0, true><<<384, 256, 0, stream>>>(
        ybuf, wt_cproj, c_proj_b, x, xout, nullptr, nullptr, nullptr, nullptr,
        BT, NE, NE, 6);

    ln_kernel<<<BT, 256, 0, stream>>>(xout, ln2_w, ln2_b, hbuf);

    // fc: M=4096 N=3072 K=768, 128-tiles -> 24*32 = 768 blocks
    mfma_gemm<128, 1, 1, false><<<768, 256, 0, stream>>>(
        hbuf, wt_fc, fc_b, nullptr, nullptr, fc_act, nullptr, nullptr, nullptr,
        BT, 4 * NE, NE, 24);

    // proj: M=4096 N=768 K=3072, 64x128 tiles -> 6*64 = 384 blocks
    mfma_gemm<64, 0, 0, true><<<384, 256, 0, stream>>>(
        fc_act, wt_proj, proj_b, xout, xout, nullptr, nullptr, nullptr, nullptr,
        BT, NE, 4 * NE, 6);
}

// Round 6
// 270.520 us; speedup vs baseline: 12.9335x; 1.1681x over previous
//
#include <hip/hip_runtime.h>
#include <hip/hip_bf16.h>
#include <math.h>

typedef unsigned short ushort;
typedef __attribute__((ext_vector_type(8))) unsigned short ushort8;
typedef __attribute__((ext_vector_type(8))) short s16x8;
typedef __attribute__((ext_vector_type(4))) float f32x4;

constexpr int NE = 768;      // N_EMBD
constexpr int NH = 12;       // heads
constexpr int HD = 64;       // head dim
constexpr int Bc = 4;
constexpr int Tc = 1024;
constexpr int BT = Bc * Tc;  // 4096 rows

__device__ __forceinline__ ushort f2bf(float f) {
    __hip_bfloat16 h = __float2bfloat16(f);
    return *reinterpret_cast<ushort*>(&h);
}
__device__ __forceinline__ float bf2f(ushort u) {
    return __uint_as_float(((unsigned)u) << 16);
}
__device__ __forceinline__ float softplus_f(float x) {
    return (x > 20.f) ? x : log1pf(__expf(x));
}
__device__ __forceinline__ float rcp_f(float x) {
#if __has_builtin(__builtin_amdgcn_rcpf)
    return __builtin_amdgcn_rcpf(x);
#else
    return 1.f / x;
#endif
}
__device__ __forceinline__ void gload16(const void* g, void* l) {
    __builtin_amdgcn_global_load_lds((const __attribute__((address_space(1))) void*)g,
                                     (__attribute__((address_space(3))) void*)l, 16, 0, 0);
}

// ---------------- LayerNorm: f32 in -> bf16 out ----------------
__global__ __launch_bounds__(256) void ln_kernel(const float* __restrict__ x,
                                                 const float* __restrict__ w,
                                                 const float* __restrict__ b,
                                                 ushort* __restrict__ out) {
    int row = blockIdx.x;
    const float* xr = x + (size_t)row * NE;
    int t = threadIdx.x;
    float v0 = xr[t], v1 = xr[t + 256], v2 = xr[t + 512];
    __shared__ float red[256], red2[256];
    red[t] = v0 + v1 + v2;
    red2[t] = v0 * v0 + v1 * v1 + v2 * v2;
    __syncthreads();
    for (int o = 128; o > 0; o >>= 1) {
        if (t < o) { red[t] += red[t + o]; red2[t] += red2[t + o]; }
        __syncthreads();
    }
    float mean = red[0] * (1.0f / NE);
    float var = red2[0] * (1.0f / NE) - mean * mean;
    float rs = rsqrtf(var + 1e-5f);
    ushort* orow = out + (size_t)row * NE;
    orow[t]       = f2bf((v0 - mean) * rs * w[t]       + b[t]);
    orow[t + 256] = f2bf((v1 - mean) * rs * w[t + 256] + b[t + 256]);
    orow[t + 512] = f2bf((v2 - mean) * rs * w[t + 512] + b[t + 512]);
}

// ---------------- weight convert: W f32 [K][N] -> Wt bf16 [N][K] ----------------
__global__ __launch_bounds__(256) void wconvert(const float* __restrict__ W,
                                                ushort* __restrict__ Wt, int K, int N) {
    __shared__ float t[32][33];
    int n0 = blockIdx.x * 32, k0 = blockIdx.y * 32;
    int c = threadIdx.x & 31, r4 = threadIdx.x >> 5;
#pragma unroll
    for (int i = 0; i < 4; ++i) {
        int r = r4 + i * 8;
        t[r][c] = W[(size_t)(k0 + r) * N + n0 + c];
    }
    __syncthreads();
#pragma unroll
    for (int i = 0; i < 4; ++i) {
        int r = r4 + i * 8;
        Wt[(size_t)(n0 + r) * K + k0 + c] = f2bf(t[c][r]);
    }
}

// ---------------- MFMA GEMM (unchanged from round 5) ----------------
template <int BM, int OUT_MODE, int ACT, bool RES>
__global__ __launch_bounds__(256) void mfma_gemm(
    const ushort* __restrict__ A, const ushort* __restrict__ Bt,
    const float* __restrict__ bias, const float* __restrict__ residual,
    float* __restrict__ Cf, ushort* __restrict__ Cb,
    ushort* __restrict__ Qo, ushort* __restrict__ Ko, ushort* __restrict__ Vo,
    int M, int N, int K, int NBX) {
    constexpr int MF = 4;
    constexpr int NF = (BM == 128) ? 4 : 2;
    constexpr int APASS = BM / 32;
    __shared__ __align__(16) ushort As[BM * 64];
    __shared__ __align__(16) ushort Bs[128 * 64];
    int tid = threadIdx.x;
    int lane = tid & 63;
    int nb = gridDim.x;
    int lin = blockIdx.x;
    int nl = (lin & 7) * (nb >> 3) + (lin >> 3);
    int bx = nl % NBX, by = nl / NBX;
    int m0 = by * BM, n0 = bx * 128;
    int wave = tid >> 6;
    int wr = (BM == 128) ? (wave >> 1) : 0;
    int wc = (BM == 128) ? (wave & 1) : wave;
    f32x4 acc[MF][NF] = {};
    int srow = tid >> 3;
    int scol = (tid & 7) ^ (srow & 7);
    const ushort* ga = A + (size_t)(m0 + srow) * K + scol * 8;
    const ushort* gb = Bt + (size_t)(n0 + srow) * K + scol * 8;
    char* lA = (char*)As + tid * 16;
    char* lB = (char*)Bs + tid * 16;
    int fr = lane & 15, g = lane >> 4;
    unsigned swz = (unsigned)((fr & 7) << 4);
    const char* abase = (const char*)As + (wr * 64 + fr) * 128;
    const char* bbase = (const char*)Bs + (wc * (NF * 16) + fr) * 128;
    for (int k0 = 0; k0 < K; k0 += 64) {
#pragma unroll
        for (int p = 0; p < APASS; ++p)
            gload16(ga + (size_t)(p * 32) * K + k0, lA + p * 4096);
#pragma unroll
        for (int p = 0; p < 4; ++p)
            gload16(gb + (size_t)(p * 32) * K + k0, lB + p * 4096);
        __syncthreads();
#pragma unroll
        for (int ks = 0; ks < 2; ++ks) {
            unsigned o = ((unsigned)(g * 16 + ks * 64)) ^ swz;
            s16x8 af[MF], bf[NF];
#pragma unroll
            for (int i = 0; i < MF; ++i) af[i] = *(const s16x8*)(abase + i * 2048 + o);
#pragma unroll
            for (int i = 0; i < NF; ++i) bf[i] = *(const s16x8*)(bbase + i * 2048 + o);
#pragma unroll
            for (int mi = 0; mi < MF; ++mi)
#pragma unroll
                for (int ni = 0; ni < NF; ++ni)
                    acc[mi][ni] = __builtin_amdgcn_mfma_f32_16x16x32_bf16(af[mi], bf[ni], acc[mi][ni], 0, 0, 0);
        }
        __syncthreads();
    }
#pragma unroll
    for (int mi = 0; mi < MF; ++mi) {
#pragma unroll
        for (int ni = 0; ni < NF; ++ni) {
#pragma unroll
            for (int j = 0; j < 4; ++j) {
                int row = m0 + wr * 64 + mi * 16 + g * 4 + j;
                int col = n0 + wc * (NF * 16) + ni * 16 + fr;
                float v = acc[mi][ni][j] + bias[col];
                if (ACT == 1) v = 0.5f * v * (1.0f + erff(v * 0.70710678118654752f));
                if (RES) v += residual[(size_t)row * N + col];
                if (OUT_MODE == 0) {
                    Cf[(size_t)row * N + col] = v;
                } else if (OUT_MODE == 1) {
                    Cb[(size_t)row * N + col] = f2bf(v);
                } else {
                    int which = col >= 1536 ? 2 : (col >= 768 ? 1 : 0);
                    int rem = col - which * 768;
                    int hh = rem >> 6, d = rem & 63;
                    int b_ = row >> 10, t_ = row & 1023;
                    if (which == 2)
                        Vo[((size_t)(b_ * NH + hh) * HD + d) * Tc + t_] = f2bf(v);
                    else {
                        ushort* dst = which == 0 ? Qo : Ko;
                        dst[((size_t)(b_ * NH + hh) * Tc + t_) * HD + d] = f2bf(v);
                    }
                }
            }
        }
    }
}

// ============ FAST attention: P-store scheme ============
// Block = one 16-row q-tile (t = 0..63) of one head; 128 thr = 2 waves (kh key-halves).
// LPT: heavy tiles (large t) dispatched first. P = exp(s*0.125-8) bf16, stored in
// MFMA-A-fragment layout: lane l elem j <-> (q = l&15, k = k0 + (l>>4)*8 + j), 1KB / 32-key step.
// panel(bh,t) = Pbuf + (bh*1056 + (t+1)^2/4)*512 ushorts; nst(t) = (t+2)>>1 steps.

__global__ __launch_bounds__(128) void attn_P(
    const ushort* __restrict__ Qp, const ushort* __restrict__ Kp,
    ushort* __restrict__ Pbuf, float* __restrict__ denom, float* __restrict__ colsum) {
    int beta = blockIdx.x;
    int tq = 63 - beta / 48;
    int bh = beta % 48;
    int tid = threadIdx.x;
    int kh = tid >> 6, lane = tid & 63, qlane = lane & 15, g = lane >> 4;
    __shared__ ushort plds[2][16][48];
    __shared__ float cs[1056];
    __shared__ float dden[2][16];
    int nst = (tq + 2) >> 1;
    int smid = (nst + 1) >> 1;
    int slo = kh ? smid : 0, shi = kh ? nst : smid;
    int kmaxc = (tq + 1) * 16;
    for (int i = tid; i < 1056; i += 128) cs[i] = 0.f;
    const ushort* Qb = Qp + (size_t)bh * Tc * HD;
    const ushort* Kb = Kp + (size_t)bh * Tc * HD;
    const ushort* qr = Qb + (size_t)(tq * 16 + qlane) * HD + g * 8;
    s16x8 qf0 = *(const s16x8*)qr;
    s16x8 qf1 = *(const s16x8*)(qr + 32);
    ushort* panel = Pbuf + ((size_t)bh * 1056 + (unsigned)(((tq + 1) * (tq + 1)) >> 2)) * 512;
    int q = tq * 16 + qlane;
    float dpart = 0.f;
    for (int s = slo; s < shi; ++s) {
        int kt0 = 2 * s, kt1 = 2 * s + 1;
        {
            const ushort* kr = Kb + (size_t)(kt0 * 16 + qlane) * HD + g * 8;
            s16x8 kf0 = *(const s16x8*)kr;
            s16x8 kf1 = *(const s16x8*)(kr + 32);
            f32x4 z = {0.f, 0.f, 0.f, 0.f};
            z = __builtin_amdgcn_mfma_f32_16x16x32_bf16(kf0, qf0, z, 0, 0, 0);
            z = __builtin_amdgcn_mfma_f32_16x16x32_bf16(kf1, qf1, z, 0, 0, 0);
#pragma unroll
            for (int j = 0; j < 4; ++j) {
                int key = kt0 * 16 + g * 4 + j;
                float p = (key <= q) ? __expf(z[j] * 0.125f - 8.f) : 0.f;
                dpart += p;
                plds[kh][qlane][g * 4 + j] = f2bf(p);
            }
        }
        if (kt1 <= tq) {
            const ushort* kr = Kb + (size_t)(kt1 * 16 + qlane) * HD + g * 8;
            s16x8 kf0 = *(const s16x8*)kr;
            s16x8 kf1 = *(const s16x8*)(kr + 32);
            f32x4 z = {0.f, 0.f, 0.f, 0.f};
            z = __builtin_amdgcn_mfma_f32_16x16x32_bf16(kf0, qf0, z, 0, 0, 0);
            z = __builtin_amdgcn_mfma_f32_16x16x32_bf16(kf1, qf1, z, 0, 0, 0);
#pragma unroll
            for (int j = 0; j < 4; ++j) {
                int key = kt1 * 16 + g * 4 + j;
                float p = (key <= q) ? __expf(z[j] * 0.125f - 8.f) : 0.f;
                dpart += p;
                plds[kh][qlane][16 + g * 4 + j] = f2bf(p);
            }
        } else {
#pragma unroll
            for (int j = 0; j < 4; ++j) plds[kh][qlane][16 + g * 4 + j] = 0;
        }
        s16x8 pa = *(const s16x8*)&plds[kh][qlane][g * 8];
        *(s16x8*)(panel + (size_t)s * 512 + lane * 8) = pa;
    }
    dpart += __shfl_xor(dpart, 16);
    dpart += __shfl_xor(dpart, 32);
    if (lane < 16) dden[kh][lane] = dpart;
    __syncthreads();
    float dsum = dden[0][qlane] + dden[1][qlane];
    if (tid < 16) denom[(size_t)bh * Tc + tq * 16 + tid] = dden[0][tid] + dden[1][tid];
    float dinvq = rcp_f(dsum);
    // sweep B: colsum from own stored P (L2-hot)
    for (int s = slo; s < shi; ++s) {
        s16x8 v8 = *(const s16x8*)(panel + (size_t)s * 512 + lane * 8);
        int k0 = s * 32 + g * 8;
#pragma unroll
        for (int j = 0; j < 8; ++j) {
            float r = bf2f((ushort)v8[j]) * dinvq;
            r += __shfl_xor(r, 1);
            r += __shfl_xor(r, 2);
            r += __shfl_xor(r, 4);
            r += __shfl_xor(r, 8);
            if (qlane == 0) cs[k0 + j] += r;
        }
    }
    __syncthreads();
    for (int i = tid; i < kmaxc; i += 128)
        atomicAdd(&colsum[(size_t)bh * Tc + i], cs[i]);
}

__global__ __launch_bounds__(128) void attn_CD(
    const ushort* __restrict__ Pbuf, const ushort* __restrict__ Vt,
    const float* __restrict__ denom, const float* __restrict__ colsum,
    const float* __restrict__ refr_in,
    const float* __restrict__ threshold, const float* __restrict__ leak,
    const float* __restrict__ steepness, const float* __restrict__ refr_strength,
    const float* __restrict__ cross_w,
    ushort* __restrict__ ybuf, float* __restrict__ refr_out) {
    int beta = blockIdx.x;
    int tq = 63 - beta / 48;
    int bh = beta % 48;
    int b = bh / NH, h = bh - b * NH;
    int tid = threadIdx.x;
    int kh = tid >> 6, lane = tid & 63, qlane = lane & 15, g = lane >> 4;
    __shared__ float eff[1056];
    __shared__ float cs[1056];
    __shared__ float msum[2][16];
    __shared__ float minvL[16];
    __shared__ float ymrg[16][68];
    int nst = (tq + 2) >> 1;
    int smid = (nst + 1) >> 1;
    int slo = kh ? smid : 0, shi = kh ? nst : smid;
    int kmaxc = (tq + 1) * 16;
    float thr = fabsf(threshold[h]) * 0.1f;
    float lk = 1.f / (1.f + __expf(-leak[h]));
    float lk1m = 1.f - lk;
    float stp = softplus_f(steepness[h]);
    float rfs = softplus_f(refr_strength[h]);
    float crw = 1.f / (1.f + __expf(-cross_w[h]));
    for (int i = tid; i < 1056; i += 128) {
        eff[i] = (i < kmaxc)
                     ? thr + rfs * (colsum[(size_t)bh * Tc + i] * (1.f / 1024.f))
                           + crw * refr_in[(size_t)b * Tc + i]
                     : 0.f;
        cs[i] = 0.f;
    }
    float dinvq = rcp_f(denom[(size_t)bh * Tc + tq * 16 + qlane]);
    __syncthreads();
    const ushort* panel = Pbuf + ((size_t)bh * 1056 + (unsigned)(((tq + 1) * (tq + 1)) >> 2)) * 512;
    // sweep C: modulated row sums
    float msp = 0.f;
#pragma unroll 2
    for (int s = slo; s < shi; ++s) {
        s16x8 v8 = *(const s16x8*)(panel + (size_t)s * 512 + lane * 8);
        int k0 = s * 32 + g * 8;
#pragma unroll
        for (int j = 0; j < 8; ++j) {
            float p = bf2f((ushort)v8[j]) * dinvq;
            float fire = rcp_f(1.f + __expf(-stp * (p - eff[k0 + j])));
            msp += p * (lk + lk1m * fire);
        }
    }
    msp += __shfl_xor(msp, 16);
    msp += __shfl_xor(msp, 32);
    if (lane < 16) msum[kh][lane] = msp;
    __syncthreads();
    if (tid < 16) minvL[tid] = rcp_f(msum[0][tid] + msum[1][tid] + 1e-8f);
    __syncthreads();
    float minvq = minvL[qlane];
    const ushort* Vh = Vt + (size_t)bh * HD * Tc;
    f32x4 accY[4] = {};
    // sweep D: PV + refractory
    for (int s = slo; s < shi; ++s) {
        s16x8 v8 = *(const s16x8*)(panel + (size_t)s * 512 + lane * 8);
        int k0 = s * 32 + g * 8;
        s16x8 pa;
#pragma unroll
        for (int j = 0; j < 8; ++j) {
            float p = bf2f((ushort)v8[j]) * dinvq;
            float fire = rcp_f(1.f + __expf(-stp * (p - eff[k0 + j])));
            float pt = p * (lk + lk1m * fire);
            pa[j] = (short)f2bf(pt);
            float r = pt * minvq;
            r += __shfl_xor(r, 1);
            r += __shfl_xor(r, 2);
            r += __shfl_xor(r, 4);
            r += __shfl_xor(r, 8);
            if (qlane == 0) cs[k0 + j] += r;
        }
#pragma unroll
        for (int dt = 0; dt < 4; ++dt) {
            const ushort* vp = Vh + (size_t)(dt * 16 + qlane) * Tc + s * 32 + g * 8;
            s16x8 vf = *(const s16x8*)vp;
            accY[dt] = __builtin_amdgcn_mfma_f32_16x16x32_bf16(pa, vf, accY[dt], 0, 0, 0);
        }
    }
    if (kh == 1) {
#pragma unroll
        for (int dt = 0; dt < 4; ++dt)
#pragma unroll
            for (int j = 0; j < 4; ++j)
                ymrg[g * 4 + j][dt * 16 + qlane] = accY[dt][j];
    }
    __syncthreads();
    if (kh == 0) {
#pragma unroll
        for (int dt = 0; dt < 4; ++dt)
#pragma unroll
            for (int j = 0; j < 4; ++j) {
                float y = (accY[dt][j] + ymrg[g * 4 + j][dt * 16 + qlane]) * minvL[g * 4 + j];
                ybuf[(size_t)(b * Tc + tq * 16 + g * 4 + j) * NE + h * 64 + dt * 16 + qlane] =
                    f2bf(y);
            }
    }
    for (int i = tid; i < kmaxc; i += 128)
        atomicAdd(&refr_out[(size_t)b * Tc + i], cs[i] * (1.f / (NH * Tc)));
}

// ============ FALLBACK attention (round-5 kernels, used if ws too small) ============
__global__ __launch_bounds__(512) void attn_den_col(
    const ushort* __restrict__ Qp, const ushort* __restrict__ Kp,
    float* __restrict__ denom, float* __restrict__ colsum) {
    int bid = blockIdx.x;
    int bh = bid % 48, qc = bid / 48;
    int tid = threadIdx.x;
    int w = tid >> 6, lane = tid & 63;
    int r = w & 3, kh = w >> 2;
    int qlane = lane & 15, g = lane >> 4;
    __shared__ float dden[2][4][16];
    __shared__ float dinvL[64];
    __shared__ float cs[1024];
    int kmax = (qc + 1) * 64;
    for (int i = tid; i < kmax; i += 512) cs[i] = 0.f;
    const ushort* Qb = Qp + (size_t)bh * Tc * HD;
    const ushort* Kb = Kp + (size_t)bh * Tc * HD;
    int q0 = qc * 64 + r * 16;
    const ushort* qr = Qb + (size_t)(q0 + qlane) * HD + g * 8;
    s16x8 qf0 = *(const s16x8*)qr;
    s16x8 qf1 = *(const s16x8*)(qr + 32);
    int nkt = qc * 4 + r + 1;
    int kmid = (nkt + 1) >> 1;
    int klo = kh ? kmid : 0, khi = kh ? nkt : kmid;
    float dpart = 0.f;
    int q = q0 + qlane;
#pragma unroll 2
    for (int kt = klo; kt < khi; ++kt) {
        const ushort* kr = Kb + (size_t)(kt * 16 + qlane) * HD + g * 8;
        s16x8 kf0 = *(const s16x8*)kr;
        s16x8 kf1 = *(const s16x8*)(kr + 32);
        f32x4 z = {0.f, 0.f, 0.f, 0.f};
        z = __builtin_amdgcn_mfma_f32_16x16x32_bf16(kf0, qf0, z, 0, 0, 0);
        z = __builtin_amdgcn_mfma_f32_16x16x32_bf16(kf1, qf1, z, 0, 0, 0);
        int keyb = kt * 16 + g * 4;
#pragma unroll
        for (int j = 0; j < 4; ++j)
            if (keyb + j <= q) dpart += __expf(z[j] * 0.125f - 8.f);
    }
    dpart += __shfl_xor(dpart, 16);
    dpart += __shfl_xor(dpart, 32);
    if (lane < 16) dden[kh][r][lane] = dpart;
    __syncthreads();
    if (tid < 64) {
        float d = dden[0][tid >> 4][tid & 15] + dden[1][tid >> 4][tid & 15];
        denom[(size_t)bh * Tc + qc * 64 + tid] = d;
        dinvL[tid] = rcp_f(d);
    }
    __syncthreads();
    float dj[4];
#pragma unroll
    for (int j = 0; j < 4; ++j) dj[j] = dinvL[r * 16 + g * 4 + j];
#pragma unroll 2
    for (int kt = klo; kt < khi; ++kt) {
        const ushort* kr = Kb + (size_t)(kt * 16 + qlane) * HD + g * 8;
        s16x8 kf0 = *(const s16x8*)kr;
        s16x8 kf1 = *(const s16x8*)(kr + 32);
        f32x4 s = {0.f, 0.f, 0.f, 0.f};
        s = __builtin_amdgcn_mfma_f32_16x16x32_bf16(qf0, kf0, s, 0, 0, 0);
        s = __builtin_amdgcn_mfma_f32_16x16x32_bf16(qf1, kf1, s, 0, 0, 0);
        int key = kt * 16 + qlane;
        float cp = 0.f;
#pragma unroll
        for (int j = 0; j < 4; ++j)
            if (key <= q0 + g * 4 + j) cp += __expf(s[j] * 0.125f - 8.f) * dj[j];
        cp += __shfl_xor(cp, 16);
        cp += __shfl_xor(cp, 32);
        if (lane < 16) atomicAdd(&cs[kt * 16 + lane], cp);
    }
    __syncthreads();
    for (int i = tid; i < kmax; i += 512)
        atomicAdd(&colsum[(size_t)bh * Tc + i], cs[i]);
}

__global__ __launch_bounds__(512) void attn_modpv(
    const ushort* __restrict__ Qp, const ushort* __restrict__ Kp,
    const ushort* __restrict__ Vt,
    const float* __restrict__ denom, const float* __restrict__ colsum,
    const float* __restrict__ refr_in,
    const float* __restrict__ threshold, const float* __restrict__ leak,
    const float* __restrict__ steepness, const float* __restrict__ refr_strength,
    const float* __restrict__ cross_w,
    ushort* __restrict__ ybuf, float* __restrict__ refr_out) {
    int bid = blockIdx.x;
    int bh = bid % 48, qc = bid / 48;
    int b = bh / NH, h = bh - b * NH;
    int tid = threadIdx.x;
    int w = tid >> 6, lane = tid & 63;
    int r = w & 3, kh = w >> 2;
    int qlane = lane & 15, g = lane >> 4;
    __shared__ float eff[1024];
    __shared__ float cs[1024];
    __shared__ float dinvL[64];
    __shared__ float msum[2][4][16];
    __shared__ float minvL[64];
    __shared__ float ymrg[4][16][65];
    __shared__ __align__(16) ushort plds[8][16][40];
    float thr = fabsf(threshold[h]) * 0.1f;
    float lk = 1.f / (1.f + __expf(-leak[h]));
    float lk1m = 1.f - lk;
    float stp = softplus_f(steepness[h]);
    float rfs = softplus_f(refr_strength[h]);
    float crw = 1.f / (1.f + __expf(-cross_w[h]));
    int kmax = (qc + 1) * 64;
    for (int i = tid; i < kmax; i += 512) {
        eff[i] = thr + rfs * (colsum[(size_t)bh * Tc + i] * (1.f / 1024.f))
                     + crw * refr_in[(size_t)b * Tc + i];
        cs[i] = 0.f;
    }
    if (tid < 64) dinvL[tid] = rcp_f(denom[(size_t)bh * Tc + qc * 64 + tid]);
    __syncthreads();
    const ushort* Qb = Qp + (size_t)bh * Tc * HD;
    const ushort* Kb = Kp + (size_t)bh * Tc * HD;
    const ushort* Vh = Vt + (size_t)bh * HD * Tc;
    int q0 = qc * 64 + r * 16;
    const ushort* qr = Qb + (size_t)(q0 + qlane) * HD + g * 8;
    s16x8 qf0 = *(const s16x8*)qr;
    s16x8 qf1 = *(const s16x8*)(qr + 32);
    int nkt = qc * 4 + r + 1;
    int kmid = (nkt + 1) >> 1;
    int klo = kh ? kmid : 0, khi = kh ? nkt : kmid;
    float di = dinvL[r * 16 + qlane];
    float msp = 0.f;
    int q = q0 + qlane;
#pragma unroll 2
    for (int kt = klo; kt < khi; ++kt) {
        const ushort* kr = Kb + (size_t)(kt * 16 + qlane) * HD + g * 8;
        s16x8 kf0 = *(const s16x8*)kr;
        s16x8 kf1 = *(const s16x8*)(kr + 32);
        f32x4 z = {0.f, 0.f, 0.f, 0.f};
        z = __builtin_amdgcn_mfma_f32_16x16x32_bf16(kf0, qf0, z, 0, 0, 0);
        z = __builtin_amdgcn_mfma_f32_16x16x32_bf16(kf1, qf1, z, 0, 0, 0);
        int keyb = kt * 16 + g * 4;
#pragma unroll
        for (int j = 0; j < 4; ++j) {
            int key = keyb + j;
            if (key <= q) {
                float p = __expf(z[j] * 0.125f - 8.f) * di;
                float fire = rcp_f(1.f + __expf(-stp * (p - eff[key])));
                msp += p * (lk + lk1m * fire);
            }
        }
    }
    msp += __shfl_xor(msp, 16);
    msp += __shfl_xor(msp, 32);
    if (lane < 16) msum[kh][r][lane] = msp;
    __syncthreads();
    if (tid < 64)
        minvL[tid] = rcp_f(msum[0][tid >> 4][tid & 15] + msum[1][tid >> 4][tid & 15] + 1e-8f);
    __syncthreads();
    float dj[4], mj[4];
#pragma unroll
    for (int j = 0; j < 4; ++j) {
        dj[j] = dinvL[r * 16 + g * 4 + j];
        mj[j] = minvL[r * 16 + g * 4 + j];
    }
    f32x4 accY[4] = {};
    for (int kt0 = klo; kt0 < khi; kt0 += 2) {
#pragma unroll
        for (int t2 = 0; t2 < 2; ++t2) {
            int kt = kt0 + t2;
            if (kt < khi) {
                const ushort* kr = Kb + (size_t)(kt * 16 + qlane) * HD + g * 8;
                s16x8 kf0 = *(const s16x8*)kr;
                s16x8 kf1 = *(const s16x8*)(kr + 32);
                f32x4 s = {0.f, 0.f, 0.f, 0.f};
                s = __builtin_amdgcn_mfma_f32_16x16x32_bf16(qf0, kf0, s, 0, 0, 0);
                s = __builtin_amdgcn_mfma_f32_16x16x32_bf16(qf1, kf1, s, 0, 0, 0);
                int key = kt * 16 + qlane;
                float ef = eff[key];
                float rp = 0.f;
#pragma unroll
                for (int j = 0; j < 4; ++j) {
                    float pv = 0.f;
                    if (key <= q0 + g * 4 + j) {
                        float p = __expf(s[j] * 0.125f - 8.f) * dj[j];
                        float fire = rcp_f(1.f + __expf(-stp * (p - ef)));
                        pv = p * (lk + lk1m * fire) * mj[j];
                    }
                    rp += pv;
                    plds[w][g * 4 + j][t2 * 16 + qlane] = f2bf(pv);
                }
                rp += __shfl_xor(rp, 16);
                rp += __shfl_xor(rp, 32);
                if (lane < 16) atomicAdd(&cs[kt * 16 + lane], rp);
            } else {
#pragma unroll
                for (int j = 0; j < 4; ++j)
                    plds[w][g * 4 + j][t2 * 16 + qlane] = 0;
            }
        }
        s16x8 pa = *(const s16x8*)&plds[w][qlane][g * 8];
#pragma unroll
        for (int dt = 0; dt < 4; ++dt) {
            const ushort* vp = Vh + (size_t)(dt * 16 + qlane) * Tc + kt0 * 16 + g * 8;
            s16x8 vf = *(const s16x8*)vp;
            accY[dt] = __builtin_amdgcn_mfma_f32_16x16x32_bf16(pa, vf, accY[dt], 0, 0, 0);
        }
    }
    if (kh == 1) {
#pragma unroll
        for (int dt = 0; dt < 4; ++dt)
#pragma unroll
            for (int j = 0; j < 4; ++j)
                ymrg[r][g * 4 + j][dt * 16 + qlane] = accY[dt][j];
    }
    __syncthreads();
    if (kh == 0) {
#pragma unroll
        for (int dt = 0; dt < 4; ++dt)
#pragma unroll
            for (int j = 0; j < 4; ++j) {
                float y = accY[dt][j] + ymrg[r][g * 4 + j][dt * 16 + qlane];
                ybuf[(size_t)(b * Tc + q0 + g * 4 + j) * NE + h * 64 + dt * 16 + qlane] =
                    f2bf(y);
            }
    }
    for (int i = tid; i < kmax; i += 512)
        atomicAdd(&refr_out[(size_t)b * Tc + i], cs[i] * (1.f / (NH * Tc)));
}

// ---------------- launcher ----------------
extern "C" void kernel_launch(void* const* d_in, const int* in_sizes, int n_in,
                              void* d_out, int out_size, void* d_ws, size_t ws_size,
                              hipStream_t stream) {
    const float* x        = (const float*)d_in[0];
    const float* refr     = (const float*)d_in[1];
    const float* ln1_w    = (const float*)d_in[2];
    const float* ln1_b    = (const float*)d_in[3];
    const float* c_attn_w = (const float*)d_in[4];
    const float* c_attn_b = (const float*)d_in[5];
    const float* c_proj_w = (const float*)d_in[6];
    const float* c_proj_b = (const float*)d_in[7];
    const float* threshold = (const float*)d_in[8];
    const float* leak      = (const float*)d_in[9];
    const float* steepness = (const float*)d_in[10];
    const float* refractory_strength = (const float*)d_in[11];
    const float* cross_layer_weight  = (const float*)d_in[12];
    const float* ln2_w    = (const float*)d_in[13];
    const float* ln2_b    = (const float*)d_in[14];
    const float* fc_w     = (const float*)d_in[15];
    const float* fc_b     = (const float*)d_in[16];
    const float* proj_w   = (const float*)d_in[17];
    const float* proj_b   = (const float*)d_in[18];

    // workspace layout (bytes)
    char* ws = (char*)d_ws;
    ushort* hbuf   = (ushort*)(ws + 0);         // bf16 [4096][768]
    ushort* qb     = (ushort*)(ws + 6291456);   // bf16 [b,h,t,d]
    ushort* kb     = (ushort*)(ws + 12582912);  // bf16 [b,h,t,d]
    ushort* vtg    = (ushort*)(ws + 18874368);  // bf16 V^T [b,h,d,t]
    ushort* ybuf   = (ushort*)(ws + 25165824);  // bf16 [4096][768]
    ushort* fc_act = (ushort*)(ws + 6291456);   // bf16 [4096][3072], overlaps q/k/v/y (post-attn)
    float*  denomb = (float*)(ws + 31457280);   // [48][1024]
    float*  colsum = (float*)(ws + 31653888);   // [48][1024]
    ushort* wt_attn  = (ushort*)(ws + 31850496);
    ushort* wt_cproj = (ushort*)(ws + 35389440);
    ushort* wt_fc    = (ushort*)(ws + 36569088);
    ushort* wt_proj  = (ushort*)(ws + 41287680);
    ushort* Pbuf     = (ushort*)(ws + 46006272); // bf16 packed causal P, 51,904,512 B
    const bool fast = ws_size >= (size_t)46006272 + (size_t)51904512;

    float* xout = (float*)d_out;
    float* refr_out = xout + (size_t)BT * NE;

    hipMemsetAsync(colsum, 0, (size_t)Bc * NH * Tc * sizeof(float), stream);
    hipMemsetAsync(refr_out, 0, (size_t)Bc * Tc * sizeof(float), stream);

    wconvert<<<dim3(2304 / 32, 768 / 32), 256, 0, stream>>>(c_attn_w, wt_attn, 768, 2304);
    wconvert<<<dim3(768 / 32, 768 / 32), 256, 0, stream>>>(c_proj_w, wt_cproj, 768, 768);
    wconvert<<<dim3(3072 / 32, 768 / 32), 256, 0, stream>>>(fc_w, wt_fc, 768, 3072);
    wconvert<<<dim3(768 / 32, 3072 / 32), 256, 0, stream>>>(proj_w, wt_proj, 3072, 768);

    ln_kernel<<<BT, 256, 0, stream>>>(x, ln1_w, ln1_b, hbuf);

    mfma_gemm<128, 2, 0, false><<<576, 256, 0, stream>>>(
        hbuf, wt_attn, c_attn_b, nullptr, nullptr, nullptr, qb, kb, vtg,
        BT, 3 * NE, NE, 18);

    if (fast) {
        attn_P<<<48 * 64, 128, 0, stream>>>(qb, kb, Pbuf, denomb, colsum);
        attn_CD<<<48 * 64, 128, 0, stream>>>(
            Pbuf, vtg, denomb, colsum, refr, threshold, leak, steepness,
            refractory_strength, cross_layer_weight, ybuf, refr_out);
    } else {
        attn_den_col<<<48 * 16, 512, 0, stream>>>(qb, kb, denomb, colsum);
        attn_modpv<<<48 * 16, 512, 0, stream>>>(
            qb, kb, vtg, denomb, colsum, refr, threshold, leak, steepness,
            refractory_strength, cross_layer_weight, ybuf, refr_out);
    }

    mfma_gemm<64, 0, 0, true><<<384, 256, 0, stream>>>(
        ybuf, wt_cproj, c_proj_b, x, xout, nullptr, nullptr, nullptr, nullptr,
        BT, NE, NE, 6);

    ln_kernel<<<BT, 256, 0, stream>>>(xout, ln2_w, ln2_b, hbuf);

    mfma_gemm<128, 1, 1, false><<<768, 256, 0, stream>>>(
        hbuf, wt_fc, fc_b, nullptr, nullptr, fc_act, nullptr, nullptr, nullptr,
        BT, 4 * NE, NE, 24);

    mfma_gemm<64, 0, 0, true><<<384, 256, 0, stream>>>(
        fc_act, wt_proj, proj_b, xout, xout, nullptr, nullptr, nullptr, nullptr,
        BT, NE, 4 * NE, 6);
}

// Round 7
// 256.937 us; speedup vs baseline: 13.6172x; 1.0529x over previous
//
#include <hip/hip_runtime.h>
#include <hip/hip_bf16.h>
#include <math.h>

typedef unsigned short ushort;
typedef __attribute__((ext_vector_type(8))) unsigned short ushort8;
typedef __attribute__((ext_vector_type(8))) short s16x8;
typedef __attribute__((ext_vector_type(4))) float f32x4;

constexpr int NE = 768;      // N_EMBD
constexpr int NH = 12;       // heads
constexpr int HD = 64;       // head dim
constexpr int Bc = 4;
constexpr int Tc = 1024;
constexpr int BT = Bc * Tc;  // 4096 rows

__device__ __forceinline__ ushort f2bf(float f) {
    __hip_bfloat16 h = __float2bfloat16(f);
    return *reinterpret_cast<ushort*>(&h);
}
__device__ __forceinline__ float bf2f(ushort u) {
    return __uint_as_float(((unsigned)u) << 16);
}
__device__ __forceinline__ float softplus_f(float x) {
    return (x > 20.f) ? x : log1pf(__expf(x));
}
__device__ __forceinline__ float rcp_f(float x) {
#if __has_builtin(__builtin_amdgcn_rcpf)
    return __builtin_amdgcn_rcpf(x);
#else
    return 1.f / x;
#endif
}
__device__ __forceinline__ void gload16(const void* g, void* l) {
    __builtin_amdgcn_global_load_lds((const __attribute__((address_space(1))) void*)g,
                                     (__attribute__((address_space(3))) void*)l, 16, 0, 0);
}

// ---------------- LayerNorm: f32 in -> bf16 out ----------------
__global__ __launch_bounds__(256) void ln_kernel(const float* __restrict__ x,
                                                 const float* __restrict__ w,
                                                 const float* __restrict__ b,
                                                 ushort* __restrict__ out) {
    int row = blockIdx.x;
    const float* xr = x + (size_t)row * NE;
    int t = threadIdx.x;
    float v0 = xr[t], v1 = xr[t + 256], v2 = xr[t + 512];
    __shared__ float red[256], red2[256];
    red[t] = v0 + v1 + v2;
    red2[t] = v0 * v0 + v1 * v1 + v2 * v2;
    __syncthreads();
    for (int o = 128; o > 0; o >>= 1) {
        if (t < o) { red[t] += red[t + o]; red2[t] += red2[t + o]; }
        __syncthreads();
    }
    float mean = red[0] * (1.0f / NE);
    float var = red2[0] * (1.0f / NE) - mean * mean;
    float rs = rsqrtf(var + 1e-5f);
    ushort* orow = out + (size_t)row * NE;
    orow[t]       = f2bf((v0 - mean) * rs * w[t]       + b[t]);
    orow[t + 256] = f2bf((v1 - mean) * rs * w[t + 256] + b[t + 256]);
    orow[t + 512] = f2bf((v2 - mean) * rs * w[t + 512] + b[t + 512]);
}

// ---------------- weight convert: W f32 [K][N] -> Wt bf16 [N][K] ----------------
__global__ __launch_bounds__(256) void wconvert(const float* __restrict__ W,
                                                ushort* __restrict__ Wt, int K, int N) {
    __shared__ float t[32][33];
    int n0 = blockIdx.x * 32, k0 = blockIdx.y * 32;
    int c = threadIdx.x & 31, r4 = threadIdx.x >> 5;
#pragma unroll
    for (int i = 0; i < 4; ++i) {
        int r = r4 + i * 8;
        t[r][c] = W[(size_t)(k0 + r) * N + n0 + c];
    }
    __syncthreads();
#pragma unroll
    for (int i = 0; i < 4; ++i) {
        int r = r4 + i * 8;
        Wt[(size_t)(n0 + r) * K + k0 + c] = f2bf(t[c][r]);
    }
}

// ---------------- MFMA GEMM: C[M][N] = A(bf16 [M][K]) @ Bt(bf16 [N][K])^T ----------------
// Tiles: (BM,BN) in {(128,128),(64,128),(64,64)}; BK = 64; 4 waves.
// LDS: row-major [row][64] bf16, 16B chunks XOR-swizzled by (row&7) via pre-swizzled
// global source + swizzled ds_read. OUT_MODE: 0=f32, 1=bf16, 2=qkv scatter (V^T).
template <int BM, int BN, int OUT_MODE, int ACT, bool RES>
__global__ __launch_bounds__(256) void mfma_gemm(
    const ushort* __restrict__ A, const ushort* __restrict__ Bt,
    const float* __restrict__ bias, const float* __restrict__ residual,
    float* __restrict__ Cf, ushort* __restrict__ Cb,
    ushort* __restrict__ Qo, ushort* __restrict__ Ko, ushort* __restrict__ Vo,
    int M, int N, int K, int NBX) {
    constexpr int NF = (BM == 128) ? 4 : 2;                        // col frags / wave
    constexpr int MF = (BM == 64 && BN == 64) ? 2 : 4;             // row frags / wave
    constexpr int WN = BN / (NF * 16);                             // waves along N
    constexpr int APASS = BM / 32, BPASS = BN / 32;
    __shared__ __align__(16) ushort As[BM * 64];
    __shared__ __align__(16) ushort Bs[BN * 64];
    int tid = threadIdx.x;
    int lane = tid & 63;
    // chunked XCD swizzle (grid %8 == 0)
    int nb = gridDim.x;
    int lin = blockIdx.x;
    int nl = (lin & 7) * (nb >> 3) + (lin >> 3);
    int bx = nl % NBX, by = nl / NBX;
    int m0 = by * BM, n0 = bx * BN;
    int wave = tid >> 6;
    int wr = wave / WN, wc = wave % WN;
    f32x4 acc[MF][NF] = {};
    int srow = tid >> 3;
    int scol = (tid & 7) ^ (srow & 7);
    const ushort* ga = A + (size_t)(m0 + srow) * K + scol * 8;
    const ushort* gb = Bt + (size_t)(n0 + srow) * K + scol * 8;
    char* lA = (char*)As + tid * 16;
    char* lB = (char*)Bs + tid * 16;
    int fr = lane & 15, g = lane >> 4;
    unsigned swz = (unsigned)((fr & 7) << 4);
    const char* abase = (const char*)As + (wr * (MF * 16) + fr) * 128;
    const char* bbase = (const char*)Bs + (wc * (NF * 16) + fr) * 128;
    for (int k0 = 0; k0 < K; k0 += 64) {
#pragma unroll
        for (int p = 0; p < APASS; ++p)
            gload16(ga + (size_t)(p * 32) * K + k0, lA + p * 4096);
#pragma unroll
        for (int p = 0; p < BPASS; ++p)
            gload16(gb + (size_t)(p * 32) * K + k0, lB + p * 4096);
        __syncthreads();
#pragma unroll
        for (int ks = 0; ks < 2; ++ks) {
            unsigned o = ((unsigned)(g * 16 + ks * 64)) ^ swz;
            s16x8 af[MF], bf[NF];
#pragma unroll
            for (int i = 0; i < MF; ++i) af[i] = *(const s16x8*)(abase + i * 2048 + o);
#pragma unroll
            for (int i = 0; i < NF; ++i) bf[i] = *(const s16x8*)(bbase + i * 2048 + o);
#pragma unroll
            for (int mi = 0; mi < MF; ++mi)
#pragma unroll
                for (int ni = 0; ni < NF; ++ni)
                    acc[mi][ni] = __builtin_amdgcn_mfma_f32_16x16x32_bf16(af[mi], bf[ni], acc[mi][ni], 0, 0, 0);
        }
        __syncthreads();
    }
#pragma unroll
    for (int mi = 0; mi < MF; ++mi) {
#pragma unroll
        for (int ni = 0; ni < NF; ++ni) {
#pragma unroll
            for (int j = 0; j < 4; ++j) {
                int row = m0 + wr * (MF * 16) + mi * 16 + g * 4 + j;
                int col = n0 + wc * (NF * 16) + ni * 16 + fr;
                float v = acc[mi][ni][j] + bias[col];
                if (ACT == 1) v = 0.5f * v * (1.0f + erff(v * 0.70710678118654752f));
                if (RES) v += residual[(size_t)row * N + col];
                if (OUT_MODE == 0) {
                    Cf[(size_t)row * N + col] = v;
                } else if (OUT_MODE == 1) {
                    Cb[(size_t)row * N + col] = f2bf(v);
                } else {
                    int which = col >= 1536 ? 2 : (col >= 768 ? 1 : 0);
                    int rem = col - which * 768;
                    int hh = rem >> 6, d = rem & 63;
                    int b_ = row >> 10, t_ = row & 1023;
                    if (which == 2)
                        Vo[((size_t)(b_ * NH + hh) * HD + d) * Tc + t_] = f2bf(v);
                    else {
                        ushort* dst = which == 0 ? Qo : Ko;
                        dst[((size_t)(b_ * NH + hh) * Tc + t_) * HD + d] = f2bf(v);
                    }
                }
            }
        }
    }
}

// ============ FAST attention: P-store scheme ============
// Block = one 16-row q-tile (t = 0..63) of one head; 128 thr = 2 waves (kh key-halves).
// LPT: heavy tiles first. P = exp(s*0.125-8) bf16 in MFMA-A-fragment layout:
// lane l elem j <-> (q = l&15, k = k0 + (l>>4)*8 + j); 1KB / 32-key step.
// panel(bh,t) = Pbuf + (bh*1056 + (t+1)^2/4)*512 ushorts; nst(t) = (t+2)>>1 steps.

__global__ __launch_bounds__(128) void attn_P(
    const ushort* __restrict__ Qp, const ushort* __restrict__ Kp,
    ushort* __restrict__ Pbuf, float* __restrict__ denom, float* __restrict__ colsum) {
    int beta = blockIdx.x;
    int tq = 63 - beta / 48;
    int bh = beta % 48;
    int tid = threadIdx.x;
    int kh = tid >> 6, lane = tid & 63, qlane = lane & 15, g = lane >> 4;
    __shared__ ushort plds[2][16][48];
    __shared__ float cs[1056];
    __shared__ float dden[2][16];
    int nst = (tq + 2) >> 1;
    int smid = (nst + 1) >> 1;
    int slo = kh ? smid : 0, shi = kh ? nst : smid;
    int kmaxc = (tq + 1) * 16;
    for (int i = tid; i < 1056; i += 128) cs[i] = 0.f;
    const ushort* Qb = Qp + (size_t)bh * Tc * HD;
    const ushort* Kb = Kp + (size_t)bh * Tc * HD;
    const ushort* qr = Qb + (size_t)(tq * 16 + qlane) * HD + g * 8;
    s16x8 qf0 = *(const s16x8*)qr;
    s16x8 qf1 = *(const s16x8*)(qr + 32);
    ushort* panel = Pbuf + ((size_t)bh * 1056 + (unsigned)(((tq + 1) * (tq + 1)) >> 2)) * 512;
    int q = tq * 16 + qlane;
    float dpart = 0.f;
    for (int s = slo; s < shi; ++s) {
        int kt0 = 2 * s, kt1 = 2 * s + 1;
        {
            const ushort* kr = Kb + (size_t)(kt0 * 16 + qlane) * HD + g * 8;
            s16x8 kf0 = *(const s16x8*)kr;
            s16x8 kf1 = *(const s16x8*)(kr + 32);
            f32x4 z = {0.f, 0.f, 0.f, 0.f};
            z = __builtin_amdgcn_mfma_f32_16x16x32_bf16(kf0, qf0, z, 0, 0, 0);
            z = __builtin_amdgcn_mfma_f32_16x16x32_bf16(kf1, qf1, z, 0, 0, 0);
#pragma unroll
            for (int j = 0; j < 4; ++j) {
                int key = kt0 * 16 + g * 4 + j;
                float p = (key <= q) ? __expf(z[j] * 0.125f - 8.f) : 0.f;
                dpart += p;
                plds[kh][qlane][g * 4 + j] = f2bf(p);
            }
        }
        if (kt1 <= tq) {
            const ushort* kr = Kb + (size_t)(kt1 * 16 + qlane) * HD + g * 8;
            s16x8 kf0 = *(const s16x8*)kr;
            s16x8 kf1 = *(const s16x8*)(kr + 32);
            f32x4 z = {0.f, 0.f, 0.f, 0.f};
            z = __builtin_amdgcn_mfma_f32_16x16x32_bf16(kf0, qf0, z, 0, 0, 0);
            z = __builtin_amdgcn_mfma_f32_16x16x32_bf16(kf1, qf1, z, 0, 0, 0);
#pragma unroll
            for (int j = 0; j < 4; ++j) {
                int key = kt1 * 16 + g * 4 + j;
                float p = (key <= q) ? __expf(z[j] * 0.125f - 8.f) : 0.f;
                dpart += p;
                plds[kh][qlane][16 + g * 4 + j] = f2bf(p);
            }
        } else {
#pragma unroll
            for (int j = 0; j < 4; ++j) plds[kh][qlane][16 + g * 4 + j] = 0;
        }
        s16x8 pa = *(const s16x8*)&plds[kh][qlane][g * 8];
        *(s16x8*)(panel + (size_t)s * 512 + lane * 8) = pa;
    }
    dpart += __shfl_xor(dpart, 16);
    dpart += __shfl_xor(dpart, 32);
    if (lane < 16) dden[kh][lane] = dpart;
    __syncthreads();
    float dsum = dden[0][qlane] + dden[1][qlane];
    if (tid < 16) denom[(size_t)bh * Tc + tq * 16 + tid] = dden[0][tid] + dden[1][tid];
    float dinvq = rcp_f(dsum);
    // sweep B: colsum from own stored P (L2-hot)
    for (int s = slo; s < shi; ++s) {
        s16x8 v8 = *(const s16x8*)(panel + (size_t)s * 512 + lane * 8);
        int k0 = s * 32 + g * 8;
#pragma unroll
        for (int j = 0; j < 8; ++j) {
            float r = bf2f((ushort)v8[j]) * dinvq;
            r += __shfl_xor(r, 1);
            r += __shfl_xor(r, 2);
            r += __shfl_xor(r, 4);
            r += __shfl_xor(r, 8);
            if (qlane == 0) cs[k0 + j] += r;
        }
    }
    __syncthreads();
    for (int i = tid; i < kmaxc; i += 128)
        atomicAdd(&colsum[(size_t)bh * Tc + i], cs[i]);
}

__global__ __launch_bounds__(128) void attn_CD(
    ushort* __restrict__ Pbuf, const ushort* __restrict__ Vt,
    const float* __restrict__ denom, const float* __restrict__ colsum,
    const float* __restrict__ refr_in,
    const float* __restrict__ threshold, const float* __restrict__ leak,
    const float* __restrict__ steepness, const float* __restrict__ refr_strength,
    const float* __restrict__ cross_w,
    ushort* __restrict__ ybuf, float* __restrict__ refr_out) {
    int beta = blockIdx.x;
    int tq = 63 - beta / 48;
    int bh = beta % 48;
    int b = bh / NH, h = bh - b * NH;
    int tid = threadIdx.x;
    int kh = tid >> 6, lane = tid & 63, qlane = lane & 15, g = lane >> 4;
    __shared__ float eff[1056];
    __shared__ float cs[1056];
    __shared__ float msum[2][16];
    __shared__ float minvL[16];
    __shared__ float ymrg[16][68];
    int nst = (tq + 2) >> 1;
    int smid = (nst + 1) >> 1;
    int slo = kh ? smid : 0, shi = kh ? nst : smid;
    int kmaxc = (tq + 1) * 16;
    float thr = fabsf(threshold[h]) * 0.1f;
    float lk = 1.f / (1.f + __expf(-leak[h]));
    float lk1m = 1.f - lk;
    float stp = softplus_f(steepness[h]);
    float rfs = softplus_f(refr_strength[h]);
    float crw = 1.f / (1.f + __expf(-cross_w[h]));
    for (int i = tid; i < 1056; i += 128) {
        eff[i] = (i < kmaxc)
                     ? thr + rfs * (colsum[(size_t)bh * Tc + i] * (1.f / 1024.f))
                           + crw * refr_in[(size_t)b * Tc + i]
                     : 0.f;
        cs[i] = 0.f;
    }
    float dinvq = rcp_f(denom[(size_t)bh * Tc + tq * 16 + qlane]);
    __syncthreads();
    ushort* panel = Pbuf + ((size_t)bh * 1056 + (unsigned)(((tq + 1) * (tq + 1)) >> 2)) * 512;
    // sweep C: LIF modulation; pt stored back into panel (bf16, fragment layout)
    float msp = 0.f;
#pragma unroll 2
    for (int s = slo; s < shi; ++s) {
        s16x8 v8 = *(const s16x8*)(panel + (size_t)s * 512 + lane * 8);
        int k0 = s * 32 + g * 8;
        s16x8 pw;
#pragma unroll
        for (int j = 0; j < 8; ++j) {
            float p = bf2f((ushort)v8[j]) * dinvq;
            float fire = rcp_f(1.f + __expf(-stp * (p - eff[k0 + j])));
            float pt = p * (lk + lk1m * fire);
            msp += pt;
            pw[j] = (short)f2bf(pt);
        }
        *(s16x8*)(panel + (size_t)s * 512 + lane * 8) = pw;
    }
    msp += __shfl_xor(msp, 16);
    msp += __shfl_xor(msp, 32);
    if (lane < 16) msum[kh][lane] = msp;
    __syncthreads();   // also drains vmcnt -> panel writes visible to own wave reads
    if (tid < 16) minvL[tid] = rcp_f(msum[0][tid] + msum[1][tid] + 1e-8f);
    __syncthreads();
    float minvq = minvL[qlane];
    const ushort* Vh = Vt + (size_t)bh * HD * Tc;
    f32x4 accY[4] = {};
    // sweep D: PV MFMA from stored pt + refractory colsum
    for (int s = slo; s < shi; ++s) {
        s16x8 pa = *(const s16x8*)(panel + (size_t)s * 512 + lane * 8);
        int k0 = s * 32 + g * 8;
#pragma unroll
        for (int j = 0; j < 8; ++j) {
            float r = bf2f((ushort)pa[j]) * minvq;
            r += __shfl_xor(r, 1);
            r += __shfl_xor(r, 2);
            r += __shfl_xor(r, 4);
            r += __shfl_xor(r, 8);
            if (qlane == 0) cs[k0 + j] += r;
        }
#pragma unroll
        for (int dt = 0; dt < 4; ++dt) {
            const ushort* vp = Vh + (size_t)(dt * 16 + qlane) * Tc + s * 32 + g * 8;
            s16x8 vf = *(const s16x8*)vp;
            accY[dt] = __builtin_amdgcn_mfma_f32_16x16x32_bf16(pa, vf, accY[dt], 0, 0, 0);
        }
    }
    if (kh == 1) {
#pragma unroll
        for (int dt = 0; dt < 4; ++dt)
#pragma unroll
            for (int j = 0; j < 4; ++j)
                ymrg[g * 4 + j][dt * 16 + qlane] = accY[dt][j];
    }
    __syncthreads();
    if (kh == 0) {
#pragma unroll
        for (int dt = 0; dt < 4; ++dt)
#pragma unroll
            for (int j = 0; j < 4; ++j) {
                float y = (accY[dt][j] + ymrg[g * 4 + j][dt * 16 + qlane]) * minvL[g * 4 + j];
                ybuf[(size_t)(b * Tc + tq * 16 + g * 4 + j) * NE + h * 64 + dt * 16 + qlane] =
                    f2bf(y);
            }
    }
    for (int i = tid; i < kmaxc; i += 128)
        atomicAdd(&refr_out[(size_t)b * Tc + i], cs[i] * (1.f / (NH * Tc)));
}

// ---------------- launcher ----------------
extern "C" void kernel_launch(void* const* d_in, const int* in_sizes, int n_in,
                              void* d_out, int out_size, void* d_ws, size_t ws_size,
                              hipStream_t stream) {
    const float* x        = (const float*)d_in[0];
    const float* refr     = (const float*)d_in[1];
    const float* ln1_w    = (const float*)d_in[2];
    const float* ln1_b    = (const float*)d_in[3];
    const float* c_attn_w = (const float*)d_in[4];
    const float* c_attn_b = (const float*)d_in[5];
    const float* c_proj_w = (const float*)d_in[6];
    const float* c_proj_b = (const float*)d_in[7];
    const float* threshold = (const float*)d_in[8];
    const float* leak      = (const float*)d_in[9];
    const float* steepness = (const float*)d_in[10];
    const float* refractory_strength = (const float*)d_in[11];
    const float* cross_layer_weight  = (const float*)d_in[12];
    const float* ln2_w    = (const float*)d_in[13];
    const float* ln2_b    = (const float*)d_in[14];
    const float* fc_w     = (const float*)d_in[15];
    const float* fc_b     = (const float*)d_in[16];
    const float* proj_w   = (const float*)d_in[17];
    const float* proj_b   = (const float*)d_in[18];

    // workspace layout (bytes)
    char* ws = (char*)d_ws;
    ushort* hbuf   = (ushort*)(ws + 0);         // bf16 [4096][768]
    ushort* qb     = (ushort*)(ws + 6291456);   // bf16 [b,h,t,d]
    ushort* kb     = (ushort*)(ws + 12582912);  // bf16 [b,h,t,d]
    ushort* vtg    = (ushort*)(ws + 18874368);  // bf16 V^T [b,h,d,t]
    ushort* ybuf   = (ushort*)(ws + 25165824);  // bf16 [4096][768]
    ushort* fc_act = (ushort*)(ws + 6291456);   // bf16 [4096][3072], overlaps q/k/v/y (post-attn)
    float*  denomb = (float*)(ws + 31457280);   // [48][1024]
    float*  colsum = (float*)(ws + 31653888);   // [48][1024]
    ushort* wt_attn  = (ushort*)(ws + 31850496);
    ushort* wt_cproj = (ushort*)(ws + 35389440);
    ushort* wt_fc    = (ushort*)(ws + 36569088);
    ushort* wt_proj  = (ushort*)(ws + 41287680);
    ushort* Pbuf     = (ushort*)(ws + 46006272); // bf16 packed causal P, 51,904,512 B

    float* xout = (float*)d_out;
    float* refr_out = xout + (size_t)BT * NE;

    hipMemsetAsync(colsum, 0, (size_t)Bc * NH * Tc * sizeof(float), stream);
    hipMemsetAsync(refr_out, 0, (size_t)Bc * Tc * sizeof(float), stream);

    wconvert<<<dim3(2304 / 32, 768 / 32), 256, 0, stream>>>(c_attn_w, wt_attn, 768, 2304);
    wconvert<<<dim3(768 / 32, 768 / 32), 256, 0, stream>>>(c_proj_w, wt_cproj, 768, 768);
    wconvert<<<dim3(3072 / 32, 768 / 32), 256, 0, stream>>>(fc_w, wt_fc, 768, 3072);
    wconvert<<<dim3(768 / 32, 3072 / 32), 256, 0, stream>>>(proj_w, wt_proj, 3072, 768);

    ln_kernel<<<BT, 256, 0, stream>>>(x, ln1_w, ln1_b, hbuf);

    // qkv: M=4096 N=2304 K=768, 64x128 tiles -> 18*64 = 1152 blocks (4.5/CU)
    mfma_gemm<64, 128, 2, 0, false><<<1152, 256, 0, stream>>>(
        hbuf, wt_attn, c_attn_b, nullptr, nullptr, nullptr, qb, kb, vtg,
        BT, 3 * NE, NE, 18);

    attn_P<<<48 * 64, 128, 0, stream>>>(qb, kb, Pbuf, denomb, colsum);
    attn_CD<<<48 * 64, 128, 0, stream>>>(
        Pbuf, vtg, denomb, colsum, refr, threshold, leak, steepness,
        refractory_strength, cross_layer_weight, ybuf, refr_out);

    // c_proj: M=4096 N=768 K=768, 64x64 tiles -> 12*64 = 768 blocks (3/CU)
    mfma_gemm<64, 64, 0, 0, true><<<768, 256, 0, stream>>>(
        ybuf, wt_cproj, c_proj_b, x, xout, nullptr, nullptr, nullptr, nullptr,
        BT, NE, NE, 12);

    ln_kernel<<<BT, 256, 0, stream>>>(xout, ln2_w, ln2_b, hbuf);

    // fc: M=4096 N=3072 K=768, 128x128 tiles -> 24*32 = 768 blocks (3/CU)
    mfma_gemm<128, 128, 1, 1, false><<<768, 256, 0, stream>>>(
        hbuf, wt_fc, fc_b, nullptr, nullptr, fc_act, nullptr, nullptr, nullptr,
        BT, 4 * NE, NE, 24);

    // proj: M=4096 N=768 K=3072, 64x64 tiles -> 12*64 = 768 blocks (3/CU)
    mfma_gemm<64, 64, 0, 0, true><<<768, 256, 0, stream>>>(
        fc_act, wt_proj, proj_b, xout, xout, nullptr, nullptr, nullptr, nullptr,
        BT, NE, 4 * NE, 12);
}